// Round 3
// baseline (1447.344 us; speedup 1.0000x reference)
//
#include <hip/hip_runtime.h>
#include <math.h>
#include <float.h>

// Round 3: reference-LITERAL implementation (no GEMM factorization).
// Each node's comb row (self || agg) is staged in LDS and dotted full-width,
// mirroring the reference computation mechanically. Plus host-side sentinel
// diagnostics for input-order / ws-size contract violations.

#define APN 105
#define UEN 4000
#define H   128
#define H2  256
#define SS  10
#define INV_NEIGH (1.0f/11.0f)

__device__ __forceinline__ float frelu(float v){ return v > 0.f ? v : 0.f; }

// ---------------- two-hop indices ----------------
// ap2ap[i,s] = adj_ue[adj_ap[i,s], s]   (values in [0,APN))
// ue2ue[u,s] = adj_ap[adj_ue[u,s], s]   (values in [0,UEN))
__global__ void k_twohop(const int* __restrict__ adj_ue, const int* __restrict__ adj_ap,
                         int* __restrict__ ap2ap, int* __restrict__ ue2ue){
  int idx = blockIdx.x*256 + threadIdx.x;
  if (idx >= (APN+UEN)*SS) return;
  if (idx < APN*SS){
    int s = idx % SS;
    ap2ap[idx] = adj_ue[adj_ap[idx]*SS + s];
  } else {
    int j = idx - APN*SS;
    int s = j % SS;
    ue2ue[j] = adj_ap[adj_ue[j]*SS + s];
  }
}

// ---------------- AP layer 1: x1,x2 -> Xap[i][0:256] ----------------
// comb1[i] = [ pl[i,:UEN] , agg(feats_ue, adj_ap)[i,:APN] ]          (x1, W1_ap1)
// comb2[i] = [ pl[i,:UEN] , agg(feats_ap, ap2ap)[i,:UEN]  ]          (x2, W1_ap2)
__global__ __launch_bounds__(256) void k_ap_layer1(
    const float* __restrict__ pl, const float* __restrict__ W1ap1,
    const float* __restrict__ W1ap2, const int* __restrict__ adj_ap,
    const int* __restrict__ ap2ap, float* __restrict__ Xap)
{
  __shared__ float plrow[UEN];
  __shared__ float agg1[112];      // [APN] : (1/11) sum_s pl[a, adj_ap[i,s]]
  __shared__ float agg2[UEN];      //        (1/11) sum_s pl[ap2ap[i,s], j]
  __shared__ int aj[SS], a2[SS];
  int i = blockIdx.x, t = threadIdx.x;
  if (t < SS){ aj[t] = adj_ap[i*SS+t]; a2[t] = ap2ap[i*SS+t]; }
  __syncthreads();
  for (int j=t; j<UEN; j+=256){
    plrow[j] = pl[(size_t)i*UEN + j];
    float s = 0.f;
    for (int q=0;q<SS;q++) s += pl[(size_t)a2[q]*UEN + j];
    agg2[j] = s*INV_NEIGH;
  }
  if (t < APN){
    float s = 0.f;
    for (int q=0;q<SS;q++) s += pl[(size_t)t*UEN + aj[q]];   // feats_ue[adj_ap[i,q], t] = pl[t, adj]
    agg1[t] = s*INV_NEIGH;
  }
  __syncthreads();
  float acc = 0.f;
  if (t < H){
    const float* w = W1ap1 + (size_t)t*(UEN+APN);
    for (int j=0;j<UEN;j++) acc = fmaf(w[j],     plrow[j], acc);
    for (int a=0;a<APN;a++) acc = fmaf(w[UEN+a], agg1[a],  acc);
  } else {
    const float* w = W1ap2 + (size_t)(t-H)*(2*UEN);
    for (int j=0;j<UEN;j++) acc = fmaf(w[j],     plrow[j], acc);
    for (int j=0;j<UEN;j++) acc = fmaf(w[UEN+j], agg2[j],  acc);
  }
  Xap[(size_t)i*H2 + t] = frelu(acc);      // X_ap[i, t]
}

// ---------------- UE layer 1: x3,x4 -> Xue[u][0:256] ----------------
// comb3[u] = [ feats_ue[u,:APN] , agg(feats_ap, adj_ue)[u,:UEN] ]    (x3, W1_ue1)
// comb4[u] = [ feats_ue[u,:APN] , agg(feats_ue, ue2ue)[u,:APN] ]     (x4, W1_ue2)
__global__ __launch_bounds__(256) void k_ue_layer1(
    const float* __restrict__ pl, const float* __restrict__ W1ue1,
    const float* __restrict__ W1ue2, const int* __restrict__ adj_ue,
    const int* __restrict__ ue2ue, float* __restrict__ Xue)
{
  __shared__ float selfr[112];     // feats_ue[u, a] = pl[a, u]
  __shared__ float agg4[112];      // (1/11) sum_s pl[a, ue2ue[u,s]]
  __shared__ float agg3[UEN];      // (1/11) sum_s pl[adj_ue[u,s], j]
  __shared__ int aj[SS], u2[SS];
  int u = blockIdx.x, t = threadIdx.x;
  if (t < SS){ aj[t] = adj_ue[u*SS+t]; u2[t] = ue2ue[u*SS+t]; }
  __syncthreads();
  for (int j=t; j<UEN; j+=256){
    float s = 0.f;
    for (int q=0;q<SS;q++) s += pl[(size_t)aj[q]*UEN + j];
    agg3[j] = s*INV_NEIGH;
  }
  if (t < APN){
    selfr[t] = pl[(size_t)t*UEN + u];
    float s = 0.f;
    for (int q=0;q<SS;q++) s += pl[(size_t)t*UEN + u2[q]];
    agg4[t] = s*INV_NEIGH;
  }
  __syncthreads();
  float acc = 0.f;
  if (t < H){
    const float* w = W1ue1 + (size_t)t*(UEN+APN);
    for (int a=0;a<APN;a++) acc = fmaf(w[a],     selfr[a], acc);
    for (int j=0;j<UEN;j++) acc = fmaf(w[APN+j], agg3[j],  acc);
  } else {
    const float* w = W1ue2 + (size_t)(t-H)*(2*APN);
    for (int a=0;a<APN;a++) acc = fmaf(w[a],     selfr[a], acc);
    for (int a=0;a<APN;a++) acc = fmaf(w[APN+a], agg4[a],  acc);
  }
  Xue[(size_t)u*H2 + t] = frelu(acc);      // X_ue[u, t]
}

// ---------------- UE layer 2: x7,x8 -> X2ue[u][0:256] ----------------
__global__ __launch_bounds__(256) void k_ue_layer2(
    const float* __restrict__ Xue, const float* __restrict__ Xap,
    const float* __restrict__ W2ue1, const float* __restrict__ W2ue2,
    const int* __restrict__ adj_ue, const int* __restrict__ ue2ue,
    float* __restrict__ X2ue)
{
  __shared__ float xr[H2], a7[H2], a8[H2];
  __shared__ int aj[SS], u2[SS];
  int u = blockIdx.x, t = threadIdx.x;
  if (t < SS){ aj[t] = adj_ue[u*SS+t]; u2[t] = ue2ue[u*SS+t]; }
  __syncthreads();
  xr[t] = Xue[(size_t)u*H2 + t];
  float s7=0.f, s8=0.f;
  for (int q=0;q<SS;q++){
    s7 += Xap[(size_t)aj[q]*H2 + t];       // agg(X_ap, adj_ue)
    s8 += Xue[(size_t)u2[q]*H2 + t];       // agg(X_ue, ue2ue)
  }
  a7[t] = s7*INV_NEIGH; a8[t] = s8*INV_NEIGH;
  __syncthreads();
  float acc = 0.f;
  if (t < H){
    const float* w = W2ue1 + (size_t)t*(2*H2);
    for (int c=0;c<H2;c++) acc = fmaf(w[c],    xr[c], acc);
    for (int c=0;c<H2;c++) acc = fmaf(w[H2+c], a7[c], acc);
  } else {
    const float* w = W2ue2 + (size_t)(t-H)*(2*H2);
    for (int c=0;c<H2;c++) acc = fmaf(w[c],    xr[c], acc);
    for (int c=0;c<H2;c++) acc = fmaf(w[H2+c], a8[c], acc);
  }
  X2ue[(size_t)u*H2 + t] = frelu(acc);     // X_ue2.T[u, t]
}

// ---------------- AP layer 2 + PC head ----------------
__global__ __launch_bounds__(256) void k_ap_layer2_head(
    const float* __restrict__ Xap, const float* __restrict__ Xue,
    const float* __restrict__ W2ap1, const float* __restrict__ W2ap2,
    const int* __restrict__ adj_ap, const int* __restrict__ ap2ap,
    const float* __restrict__ wap1, const float* __restrict__ wap2,
    const float* __restrict__ bais_ap, float* __restrict__ out_pc)
{
  __shared__ float xa[H2], a5[H2], a6[H2], xs2[H2], red[256];
  __shared__ int aj[SS], a2i[SS];
  int i = blockIdx.x, t = threadIdx.x;
  if (t < SS){ aj[t] = adj_ap[i*SS+t]; a2i[t] = ap2ap[i*SS+t]; }
  __syncthreads();
  xa[t] = Xap[(size_t)i*H2+t];
  float s5=0.f, s6=0.f;
  for (int q=0;q<SS;q++){
    s5 += Xue[(size_t)aj[q]*H2 + t];       // agg(X_ue, adj_ap)
    s6 += Xap[(size_t)a2i[q]*H2 + t];      // agg(X_ap, ap2ap)
  }
  a5[t]=s5*INV_NEIGH; a6[t]=s6*INV_NEIGH;
  __syncthreads();
  float acc=0.f;
  if (t < H){
    const float* w = W2ap1 + (size_t)t*(2*H2);
    for (int c=0;c<H2;c++) acc = fmaf(w[c],    xa[c], acc);
    for (int c=0;c<H2;c++) acc = fmaf(w[H2+c], a5[c], acc);
  } else {
    const float* w = W2ap2 + (size_t)(t-H)*(2*H2);
    for (int c=0;c<H2;c++) acc = fmaf(w[c],    xa[c], acc);
    for (int c=0;c<H2;c++) acc = fmaf(w[H2+c], a6[c], acc);
  }
  xs2[t] = frelu(acc);                     // X_ap2[t, i]
  __syncthreads();
  float hid = bais_ap[i];
  const float* wr1 = wap1 + (size_t)t*H2;
  for (int c=0;c<H2;c++) hid = fmaf(wr1[c], xs2[c], hid);
  red[t] = wap2[t]*hid;
  __syncthreads();
  for (int o=128;o>0;o>>=1){ if (t<o) red[t]+=red[t+o]; __syncthreads(); }
  if (t==0) out_pc[i] = 1.f/(1.f+expf(-red[0]));
}

// ---------------- BatchNorm over UEN rows of X2ue ----------------
__global__ __launch_bounds__(256) void k_bn_part(const float* __restrict__ X2ue,
                                                 float* __restrict__ part){
  int b = blockIdx.x, c = threadIdx.x;
  float s=0.f, s2=0.f;
  for (int u = b*125; u < (b+1)*125; u++){
    float v = X2ue[(size_t)u*H2 + c];
    s += v; s2 += v*v;
  }
  part[b*512 + c] = s;
  part[b*512 + 256 + c] = s2;
}

__global__ __launch_bounds__(256) void k_bn_final(
    const float* __restrict__ part, const float* __restrict__ gamma,
    const float* __restrict__ beta, const float* __restrict__ wue,
    float* __restrict__ scsh, float* __restrict__ out_scalar)
{
  __shared__ float red[256];
  int t = threadIdx.x;
  float s=0.f, s2=0.f;
  for (int b=0;b<32;b++){ s += part[b*512+t]; s2 += part[b*512+256+t]; }
  float mean = s*(1.f/UEN);
  float var  = s2*(1.f/UEN) - mean*mean;     // biased, training-mode BN
  float sc = gamma[t]*rsqrtf(var + 1e-5f);
  scsh[t]    = sc;
  scsh[H2+t] = beta[t] - mean*sc;
  float vsum = 0.f;
  if (t < APN){
    const float* wr = wue + (size_t)t*H2;
    float S=0.f, S2=0.f;
    for (int c=0;c<H2;c++){ float w=wr[c]; S+=w; S2+=w*w; }
    vsum = (S2 - S*S*(1.f/H2)) * (1.f/(H2-1));   // ddof=1
  }
  red[t]=vsum; __syncthreads();
  for (int o=128;o>0;o>>=1){ if (t<o) red[t]+=red[t+o]; __syncthreads(); }
  if (t==0) out_scalar[0]=red[0];
}

__global__ __launch_bounds__(256) void k_bn_apply(float* __restrict__ X2ue,
                                                  const float* __restrict__ scsh){
  int u = blockIdx.x, t = threadIdx.x;
  size_t idx = (size_t)u*H2+t;
  X2ue[idx] = X2ue[idx]*scsh[t] + scsh[H2+t];   // xbn
}

// ---------------- UA head: literal wue @ xbn.T + softmaxes ----------------
__global__ __launch_bounds__(128) void k_ua_head(
    const float* __restrict__ xbn, const float* __restrict__ wue,
    const float* __restrict__ bais_ue, float* __restrict__ out)
{
  __shared__ float xs[4][H2];
  __shared__ float rmax[128], rmin[128], rs1[128], rs2[128];
  int u0 = blockIdx.x*4, t = threadIdx.x;
  #pragma unroll
  for (int q=0;q<4;q++){
    xs[q][t]     = xbn[(size_t)(u0+q)*H2 + t];
    xs[q][t+128] = xbn[(size_t)(u0+q)*H2 + t + 128];
  }
  __syncthreads();
  int a = t;
  float acc[4] = {0.f,0.f,0.f,0.f};
  if (a < APN){
    const float* wr = wue + (size_t)a*H2;
    for (int c=0;c<H2;c++){
      float w = wr[c];
      acc[0] = fmaf(w, xs[0][c], acc[0]);
      acc[1] = fmaf(w, xs[1][c], acc[1]);
      acc[2] = fmaf(w, xs[2][c], acc[2]);
      acc[3] = fmaf(w, xs[3][c], acc[3]);
    }
    #pragma unroll
    for (int q=0;q<4;q++) acc[q] += bais_ue[u0+q];
  }
  for (int q=0;q<4;q++){
    rmax[t] = (a<APN) ? acc[q] : -FLT_MAX;
    rmin[t] = (a<APN) ? acc[q] :  FLT_MAX;
    __syncthreads();
    for (int o=64;o>0;o>>=1){
      if (t<o){ rmax[t]=fmaxf(rmax[t],rmax[t+o]); rmin[t]=fminf(rmin[t],rmin[t+o]); }
      __syncthreads();
    }
    float mx = rmax[0], mn = rmin[0];
    __syncthreads();
    float nor = (a<APN) ? (acc[q]-mx)/(mx-mn) : 0.f;   // in [-1, 0], row max -> 0
    float e1 = (a<APN) ? expf(nor*1000.f) : 0.f;
    float e2 = (a<APN) ? expf(nor)        : 0.f;
    rs1[t]=e1; rs2[t]=e2;
    __syncthreads();
    for (int o=64;o>0;o>>=1){
      if (t<o){ rs1[t]+=rs1[t+o]; rs2[t]+=rs2[t+o]; }
      __syncthreads();
    }
    float s1=rs1[0], s2=rs2[0];
    __syncthreads();
    if (a<APN){
      size_t u = u0+q;
      out[u*APN + a]                     = acc[q];   // UA_ori
      out[(size_t)UEN*APN   + u*APN + a] = e1/s1;    // UA_de
      out[(size_t)2*UEN*APN + u*APN + a] = e2/s2;    // UA_st
    }
  }
}

// ---------------- sentinel (harness-contract diagnostics) ----------------
__global__ void k_poison(float* __restrict__ out, float flag){
  if (flag > 0.5f) out[0] = flag;
}

extern "C" void kernel_launch(void* const* d_in, const int* in_sizes, int n_in,
                              void* d_out, int out_size, void* d_ws, size_t ws_size,
                              hipStream_t stream) {
  const float* pl      = (const float*)d_in[0];
  const int*   adj_ue  = (const int*)d_in[2];
  const int*   adj_ap  = (const int*)d_in[3];
  const float* W1ap1   = (const float*)d_in[4];
  const float* W1ap2   = (const float*)d_in[5];
  const float* W1ue1   = (const float*)d_in[6];
  const float* W1ue2   = (const float*)d_in[7];
  const float* W2ap1   = (const float*)d_in[8];
  const float* W2ap2   = (const float*)d_in[9];
  const float* W2ue1   = (const float*)d_in[10];
  const float* W2ue2   = (const float*)d_in[11];
  const float* wap1    = (const float*)d_in[12];
  const float* wap2    = (const float*)d_in[13];
  const float* bais_ap = (const float*)d_in[14];
  const float* wue     = (const float*)d_in[15];
  const float* bais_ue = (const float*)d_in[16];
  const float* gamma   = (const float*)d_in[17];
  const float* beta    = (const float*)d_in[18];
  float* out = (float*)d_out;

  char* ws = (char*)d_ws;
  size_t off = 0;
  auto alloc = [&](size_t bytes)->char*{
    char* p = ws + off; off += (bytes + 255) & ~(size_t)255; return p;
  };
  int*   ap2ap = (int*)alloc(APN*SS*4);
  int*   ue2ue = (int*)alloc(UEN*SS*4);
  float* Xap   = (float*)alloc((size_t)APN*H2*4);
  float* Xue   = (float*)alloc((size_t)UEN*H2*4);
  float* X2ue  = (float*)alloc((size_t)UEN*H2*4);
  float* part  = (float*)alloc(32*512*4);
  float* scsh  = (float*)alloc(2*H2*4);
  size_t need = off;

  // ---- harness-contract sentinels (computed host-side, deterministic) ----
  static const int exp_sizes[19] = {420000,4000,40000,1050,525440,1024000,525440,
                                    26880,65536,65536,65536,65536,65536,256,105,
                                    26880,4000,256,256};
  float flag = 0.f;
  if (n_in != 19) flag = 1e9f + 99.f;
  else {
    for (int i2 = 0; i2 < 19; i2++)
      if (in_sizes[i2] != exp_sizes[i2]){ flag = 1e9f + (float)i2; break; }
  }
  if (ws_size < need) flag += 2e9f;
  (void)out_size;

  k_twohop        <<<dim3(((APN+UEN)*SS+255)/256), 256, 0, stream>>>(adj_ue, adj_ap, ap2ap, ue2ue);
  k_ap_layer1     <<<dim3(APN), 256, 0, stream>>>(pl, W1ap1, W1ap2, adj_ap, ap2ap, Xap);
  k_ue_layer1     <<<dim3(UEN), 256, 0, stream>>>(pl, W1ue1, W1ue2, adj_ue, ue2ue, Xue);
  k_ue_layer2     <<<dim3(UEN), 256, 0, stream>>>(Xue, Xap, W2ue1, W2ue2, adj_ue, ue2ue, X2ue);
  k_ap_layer2_head<<<dim3(APN), 256, 0, stream>>>(Xap, Xue, W2ap1, W2ap2, adj_ap, ap2ap,
                                                  wap1, wap2, bais_ap,
                                                  out + (size_t)3*UEN*APN);
  k_bn_part       <<<dim3(32), 256, 0, stream>>>(X2ue, part);
  k_bn_final      <<<dim3(1), 256, 0, stream>>>(part, gamma, beta, wue, scsh,
                                                out + (size_t)3*UEN*APN + APN);
  k_bn_apply      <<<dim3(UEN), 256, 0, stream>>>(X2ue, scsh);
  k_ua_head       <<<dim3(UEN/4), 128, 0, stream>>>(X2ue, wue, bais_ue, out);
  k_poison        <<<dim3(1), 1, 0, stream>>>(out, flag);
}

// Round 4
// 766.693 us; speedup vs baseline: 1.8878x; 1.8878x over previous
//
#include <hip/hip_runtime.h>
#include <math.h>
#include <float.h>

// Round 4: green baseline (round 3 literal) + ONE factorization: x3's agg3
// term goes through precomputed P3 (105x128). Plus 4-way accumulator unrolls
// on the remaining serial dot chains (pure FP reorder).

#define APN 105
#define UEN 4000
#define H   128
#define H2  256
#define SS  10
#define INV_NEIGH (1.0f/11.0f)

__device__ __forceinline__ float frelu(float v){ return v > 0.f ? v : 0.f; }

// ---------------- two-hop indices ----------------
__global__ void k_twohop(const int* __restrict__ adj_ue, const int* __restrict__ adj_ap,
                         int* __restrict__ ap2ap, int* __restrict__ ue2ue){
  int idx = blockIdx.x*256 + threadIdx.x;
  if (idx >= (APN+UEN)*SS) return;
  if (idx < APN*SS){
    int s = idx % SS;
    ap2ap[idx] = adj_ue[adj_ap[idx]*SS + s];
  } else {
    int j = idx - APN*SS;
    int s = j % SS;
    ue2ue[j] = adj_ap[adj_ue[j]*SS + s];
  }
}

// ---------------- P3 precompute: P3t[n][h] = sum_j W1ue1[h, APN+j]*pl[n, j] ----------------
// n < APN. This factors x3's aggregated term through the 10-neighbor gather.
__global__ __launch_bounds__(128) void k_p3(
    const float* __restrict__ pl, const float* __restrict__ W1ue1,
    float* __restrict__ P3t)
{
  __shared__ float plrow[UEN];
  int n = blockIdx.x, t = threadIdx.x;
  for (int j=t; j<UEN; j+=128) plrow[j] = pl[(size_t)n*UEN + j];
  __syncthreads();
  const float* w = W1ue1 + (size_t)t*(UEN+APN) + APN;
  float s0=0.f,s1=0.f,s2=0.f,s3=0.f;
  for (int j=0;j<UEN;j+=4){
    s0 = fmaf(w[j  ], plrow[j  ], s0);
    s1 = fmaf(w[j+1], plrow[j+1], s1);
    s2 = fmaf(w[j+2], plrow[j+2], s2);
    s3 = fmaf(w[j+3], plrow[j+3], s3);
  }
  P3t[(size_t)n*H + t] = (s0+s1)+(s2+s3);
}

// ---------------- AP layer 1: x1,x2 -> Xap[i][0:256] (literal, unrolled) ----------------
__global__ __launch_bounds__(256) void k_ap_layer1(
    const float* __restrict__ pl, const float* __restrict__ W1ap1,
    const float* __restrict__ W1ap2, const int* __restrict__ adj_ap,
    const int* __restrict__ ap2ap, float* __restrict__ Xap)
{
  __shared__ float plrow[UEN];
  __shared__ float agg1[112];
  __shared__ float agg2[UEN];
  __shared__ int aj[SS], a2[SS];
  int i = blockIdx.x, t = threadIdx.x;
  if (t < SS){ aj[t] = adj_ap[i*SS+t]; a2[t] = ap2ap[i*SS+t]; }
  __syncthreads();
  for (int j=t; j<UEN; j+=256){
    plrow[j] = pl[(size_t)i*UEN + j];
    float s = 0.f;
    for (int q=0;q<SS;q++) s += pl[(size_t)a2[q]*UEN + j];
    agg2[j] = s*INV_NEIGH;
  }
  if (t < APN){
    float s = 0.f;
    for (int q=0;q<SS;q++) s += pl[(size_t)t*UEN + aj[q]];
    agg1[t] = s*INV_NEIGH;
  }
  __syncthreads();
  float acc;
  if (t < H){
    const float* w = W1ap1 + (size_t)t*(UEN+APN);
    float s0=0.f,s1=0.f,s2=0.f,s3=0.f;
    for (int j=0;j<UEN;j+=4){
      s0 = fmaf(w[j  ], plrow[j  ], s0);
      s1 = fmaf(w[j+1], plrow[j+1], s1);
      s2 = fmaf(w[j+2], plrow[j+2], s2);
      s3 = fmaf(w[j+3], plrow[j+3], s3);
    }
    acc = (s0+s1)+(s2+s3);
    for (int a=0;a<APN;a++) acc = fmaf(w[UEN+a], agg1[a], acc);
  } else {
    const float* w = W1ap2 + (size_t)(t-H)*(2*UEN);
    float s0=0.f,s1=0.f,s2=0.f,s3=0.f;
    for (int j=0;j<UEN;j+=4){
      s0 = fmaf(w[j  ],     plrow[j  ], s0);
      s1 = fmaf(w[j+1],     plrow[j+1], s1);
      s2 = fmaf(w[j+2],     plrow[j+2], s2);
      s3 = fmaf(w[j+3],     plrow[j+3], s3);
    }
    for (int j=0;j<UEN;j+=4){
      s0 = fmaf(w[UEN+j  ], agg2[j  ], s0);
      s1 = fmaf(w[UEN+j+1], agg2[j+1], s1);
      s2 = fmaf(w[UEN+j+2], agg2[j+2], s2);
      s3 = fmaf(w[UEN+j+3], agg2[j+3], s3);
    }
    acc = (s0+s1)+(s2+s3);
  }
  Xap[(size_t)i*H2 + t] = frelu(acc);
}

// ---------------- UE layer 1 v2: x3 via P3 gather; x4 literal ----------------
__global__ __launch_bounds__(256) void k_ue_layer1_v2(
    const float* __restrict__ pl, const float* __restrict__ W1ue1,
    const float* __restrict__ W1ue2, const int* __restrict__ adj_ue,
    const int* __restrict__ ue2ue, const float* __restrict__ P3t,
    float* __restrict__ Xue)
{
  __shared__ float selfr[112];     // feats_ue[u, a] = pl[a, u]
  __shared__ float agg4[112];      // (1/11) sum_s pl[a, ue2ue[u,s]]
  __shared__ int aj[SS], u2[SS];
  int u = blockIdx.x, t = threadIdx.x;
  if (t < SS){ aj[t] = adj_ue[u*SS+t]; u2[t] = ue2ue[u*SS+t]; }
  __syncthreads();
  if (t < APN){
    selfr[t] = pl[(size_t)t*UEN + u];
    float s = 0.f;
    for (int q=0;q<SS;q++) s += pl[(size_t)t*UEN + u2[q]];
    agg4[t] = s*INV_NEIGH;
  }
  __syncthreads();
  float acc = 0.f;
  if (t < H){
    const float* w = W1ue1 + (size_t)t*(UEN+APN);
    for (int a=0;a<APN;a++) acc = fmaf(w[a], selfr[a], acc);
    float g = 0.f;
    for (int q=0;q<SS;q++) g += P3t[(size_t)aj[q]*H + t];
    acc += g*INV_NEIGH;
  } else {
    const float* w = W1ue2 + (size_t)(t-H)*(2*APN);
    for (int a=0;a<APN;a++) acc = fmaf(w[a],     selfr[a], acc);
    for (int a=0;a<APN;a++) acc = fmaf(w[APN+a], agg4[a],  acc);
  }
  Xue[(size_t)u*H2 + t] = frelu(acc);
}

// ---------------- UE layer 2: x7,x8 (literal, unrolled) ----------------
__global__ __launch_bounds__(256) void k_ue_layer2(
    const float* __restrict__ Xue, const float* __restrict__ Xap,
    const float* __restrict__ W2ue1, const float* __restrict__ W2ue2,
    const int* __restrict__ adj_ue, const int* __restrict__ ue2ue,
    float* __restrict__ X2ue)
{
  __shared__ float xr[H2], a7[H2], a8[H2];
  __shared__ int aj[SS], u2[SS];
  int u = blockIdx.x, t = threadIdx.x;
  if (t < SS){ aj[t] = adj_ue[u*SS+t]; u2[t] = ue2ue[u*SS+t]; }
  __syncthreads();
  xr[t] = Xue[(size_t)u*H2 + t];
  float s7=0.f, s8=0.f;
  for (int q=0;q<SS;q++){
    s7 += Xap[(size_t)aj[q]*H2 + t];
    s8 += Xue[(size_t)u2[q]*H2 + t];
  }
  a7[t] = s7*INV_NEIGH; a8[t] = s8*INV_NEIGH;
  __syncthreads();
  const float* w; const float* agg;
  if (t < H){ w = W2ue1 + (size_t)t*(2*H2);     agg = a7; }
  else      { w = W2ue2 + (size_t)(t-H)*(2*H2); agg = a8; }
  float s0=0.f,s1=0.f,s2=0.f,s3=0.f;
  for (int c=0;c<H2;c+=4){
    s0 = fmaf(w[c  ], xr[c  ], s0);
    s1 = fmaf(w[c+1], xr[c+1], s1);
    s2 = fmaf(w[c+2], xr[c+2], s2);
    s3 = fmaf(w[c+3], xr[c+3], s3);
  }
  for (int c=0;c<H2;c+=4){
    s0 = fmaf(w[H2+c  ], agg[c  ], s0);
    s1 = fmaf(w[H2+c+1], agg[c+1], s1);
    s2 = fmaf(w[H2+c+2], agg[c+2], s2);
    s3 = fmaf(w[H2+c+3], agg[c+3], s3);
  }
  X2ue[(size_t)u*H2 + t] = frelu((s0+s1)+(s2+s3));
}

// ---------------- AP layer 2 + PC head (literal, unrolled) ----------------
__global__ __launch_bounds__(256) void k_ap_layer2_head(
    const float* __restrict__ Xap, const float* __restrict__ Xue,
    const float* __restrict__ W2ap1, const float* __restrict__ W2ap2,
    const int* __restrict__ adj_ap, const int* __restrict__ ap2ap,
    const float* __restrict__ wap1, const float* __restrict__ wap2,
    const float* __restrict__ bais_ap, float* __restrict__ out_pc)
{
  __shared__ float xa[H2], a5[H2], a6[H2], xs2[H2], red[256];
  __shared__ int aj[SS], a2i[SS];
  int i = blockIdx.x, t = threadIdx.x;
  if (t < SS){ aj[t] = adj_ap[i*SS+t]; a2i[t] = ap2ap[i*SS+t]; }
  __syncthreads();
  xa[t] = Xap[(size_t)i*H2+t];
  float s5=0.f, s6=0.f;
  for (int q=0;q<SS;q++){
    s5 += Xue[(size_t)aj[q]*H2 + t];
    s6 += Xap[(size_t)a2i[q]*H2 + t];
  }
  a5[t]=s5*INV_NEIGH; a6[t]=s6*INV_NEIGH;
  __syncthreads();
  const float* w; const float* agg;
  if (t < H){ w = W2ap1 + (size_t)t*(2*H2);     agg = a5; }
  else      { w = W2ap2 + (size_t)(t-H)*(2*H2); agg = a6; }
  float s0=0.f,s1=0.f,s2=0.f,s3=0.f;
  for (int c=0;c<H2;c+=4){
    s0 = fmaf(w[c  ], xa[c  ], s0);
    s1 = fmaf(w[c+1], xa[c+1], s1);
    s2 = fmaf(w[c+2], xa[c+2], s2);
    s3 = fmaf(w[c+3], xa[c+3], s3);
  }
  for (int c=0;c<H2;c+=4){
    s0 = fmaf(w[H2+c  ], agg[c  ], s0);
    s1 = fmaf(w[H2+c+1], agg[c+1], s1);
    s2 = fmaf(w[H2+c+2], agg[c+2], s2);
    s3 = fmaf(w[H2+c+3], agg[c+3], s3);
  }
  xs2[t] = frelu((s0+s1)+(s2+s3));           // X_ap2[t, i]
  __syncthreads();
  float hid = bais_ap[i];
  const float* wr1 = wap1 + (size_t)t*H2;
  for (int c=0;c<H2;c++) hid = fmaf(wr1[c], xs2[c], hid);
  red[t] = wap2[t]*hid;
  __syncthreads();
  for (int o=128;o>0;o>>=1){ if (t<o) red[t]+=red[t+o]; __syncthreads(); }
  if (t==0) out_pc[i] = 1.f/(1.f+expf(-red[0]));
}

// ---------------- BatchNorm over UEN rows of X2ue ----------------
__global__ __launch_bounds__(256) void k_bn_part(const float* __restrict__ X2ue,
                                                 float* __restrict__ part){
  int b = blockIdx.x, c = threadIdx.x;
  float s=0.f, s2=0.f;
  for (int u = b*125; u < (b+1)*125; u++){
    float v = X2ue[(size_t)u*H2 + c];
    s += v; s2 += v*v;
  }
  part[b*512 + c] = s;
  part[b*512 + 256 + c] = s2;
}

__global__ __launch_bounds__(256) void k_bn_final(
    const float* __restrict__ part, const float* __restrict__ gamma,
    const float* __restrict__ beta, const float* __restrict__ wue,
    float* __restrict__ scsh, float* __restrict__ out_scalar)
{
  __shared__ float red[256];
  int t = threadIdx.x;
  float s=0.f, s2=0.f;
  for (int b=0;b<32;b++){ s += part[b*512+t]; s2 += part[b*512+256+t]; }
  float mean = s*(1.f/UEN);
  float var  = s2*(1.f/UEN) - mean*mean;     // biased, training-mode BN
  float sc = gamma[t]*rsqrtf(var + 1e-5f);
  scsh[t]    = sc;
  scsh[H2+t] = beta[t] - mean*sc;
  float vsum = 0.f;
  if (t < APN){
    const float* wr = wue + (size_t)t*H2;
    float S=0.f, S2=0.f;
    for (int c=0;c<H2;c++){ float w=wr[c]; S+=w; S2+=w*w; }
    vsum = (S2 - S*S*(1.f/H2)) * (1.f/(H2-1));   // ddof=1
  }
  red[t]=vsum; __syncthreads();
  for (int o=128;o>0;o>>=1){ if (t<o) red[t]+=red[t+o]; __syncthreads(); }
  if (t==0) out_scalar[0]=red[0];
}

__global__ __launch_bounds__(256) void k_bn_apply(float* __restrict__ X2ue,
                                                  const float* __restrict__ scsh){
  int u = blockIdx.x, t = threadIdx.x;
  size_t idx = (size_t)u*H2+t;
  X2ue[idx] = X2ue[idx]*scsh[t] + scsh[H2+t];
}

// ---------------- UA head ----------------
__global__ __launch_bounds__(128) void k_ua_head(
    const float* __restrict__ xbn, const float* __restrict__ wue,
    const float* __restrict__ bais_ue, float* __restrict__ out)
{
  __shared__ float xs[4][H2];
  __shared__ float rmax[128], rmin[128], rs1[128], rs2[128];
  int u0 = blockIdx.x*4, t = threadIdx.x;
  #pragma unroll
  for (int q=0;q<4;q++){
    xs[q][t]     = xbn[(size_t)(u0+q)*H2 + t];
    xs[q][t+128] = xbn[(size_t)(u0+q)*H2 + t + 128];
  }
  __syncthreads();
  int a = t;
  float acc[4] = {0.f,0.f,0.f,0.f};
  if (a < APN){
    const float* wr = wue + (size_t)a*H2;
    for (int c=0;c<H2;c++){
      float w = wr[c];
      acc[0] = fmaf(w, xs[0][c], acc[0]);
      acc[1] = fmaf(w, xs[1][c], acc[1]);
      acc[2] = fmaf(w, xs[2][c], acc[2]);
      acc[3] = fmaf(w, xs[3][c], acc[3]);
    }
    #pragma unroll
    for (int q=0;q<4;q++) acc[q] += bais_ue[u0+q];
  }
  for (int q=0;q<4;q++){
    rmax[t] = (a<APN) ? acc[q] : -FLT_MAX;
    rmin[t] = (a<APN) ? acc[q] :  FLT_MAX;
    __syncthreads();
    for (int o=64;o>0;o>>=1){
      if (t<o){ rmax[t]=fmaxf(rmax[t],rmax[t+o]); rmin[t]=fminf(rmin[t],rmin[t+o]); }
      __syncthreads();
    }
    float mx = rmax[0], mn = rmin[0];
    __syncthreads();
    float nor = (a<APN) ? (acc[q]-mx)/(mx-mn) : 0.f;
    float e1 = (a<APN) ? expf(nor*1000.f) : 0.f;
    float e2 = (a<APN) ? expf(nor)        : 0.f;
    rs1[t]=e1; rs2[t]=e2;
    __syncthreads();
    for (int o=64;o>0;o>>=1){
      if (t<o){ rs1[t]+=rs1[t+o]; rs2[t]+=rs2[t+o]; }
      __syncthreads();
    }
    float s1=rs1[0], s2=rs2[0];
    __syncthreads();
    if (a<APN){
      size_t u = u0+q;
      out[u*APN + a]                     = acc[q];   // UA_ori
      out[(size_t)UEN*APN   + u*APN + a] = e1/s1;    // UA_de
      out[(size_t)2*UEN*APN + u*APN + a] = e2/s2;    // UA_st
    }
  }
}

extern "C" void kernel_launch(void* const* d_in, const int* in_sizes, int n_in,
                              void* d_out, int out_size, void* d_ws, size_t ws_size,
                              hipStream_t stream) {
  const float* pl      = (const float*)d_in[0];
  const int*   adj_ue  = (const int*)d_in[2];
  const int*   adj_ap  = (const int*)d_in[3];
  const float* W1ap1   = (const float*)d_in[4];
  const float* W1ap2   = (const float*)d_in[5];
  const float* W1ue1   = (const float*)d_in[6];
  const float* W1ue2   = (const float*)d_in[7];
  const float* W2ap1   = (const float*)d_in[8];
  const float* W2ap2   = (const float*)d_in[9];
  const float* W2ue1   = (const float*)d_in[10];
  const float* W2ue2   = (const float*)d_in[11];
  const float* wap1    = (const float*)d_in[12];
  const float* wap2    = (const float*)d_in[13];
  const float* bais_ap = (const float*)d_in[14];
  const float* wue     = (const float*)d_in[15];
  const float* bais_ue = (const float*)d_in[16];
  const float* gamma   = (const float*)d_in[17];
  const float* beta    = (const float*)d_in[18];
  float* out = (float*)d_out;
  (void)in_sizes; (void)n_in; (void)out_size; (void)ws_size;

  char* ws = (char*)d_ws;
  size_t off = 0;
  auto alloc = [&](size_t bytes)->char*{
    char* p = ws + off; off += (bytes + 255) & ~(size_t)255; return p;
  };
  int*   ap2ap = (int*)alloc(APN*SS*4);
  int*   ue2ue = (int*)alloc(UEN*SS*4);
  float* Xap   = (float*)alloc((size_t)APN*H2*4);
  float* Xue   = (float*)alloc((size_t)UEN*H2*4);
  float* X2ue  = (float*)alloc((size_t)UEN*H2*4);
  float* part  = (float*)alloc(32*512*4);
  float* scsh  = (float*)alloc(2*H2*4);
  float* P3t   = (float*)alloc((size_t)APN*H*4);

  k_twohop        <<<dim3(((APN+UEN)*SS+255)/256), 256, 0, stream>>>(adj_ue, adj_ap, ap2ap, ue2ue);
  k_p3            <<<dim3(APN), 128, 0, stream>>>(pl, W1ue1, P3t);
  k_ap_layer1     <<<dim3(APN), 256, 0, stream>>>(pl, W1ap1, W1ap2, adj_ap, ap2ap, Xap);
  k_ue_layer1_v2  <<<dim3(UEN), 256, 0, stream>>>(pl, W1ue1, W1ue2, adj_ue, ue2ue, P3t, Xue);
  k_ue_layer2     <<<dim3(UEN), 256, 0, stream>>>(Xue, Xap, W2ue1, W2ue2, adj_ue, ue2ue, X2ue);
  k_ap_layer2_head<<<dim3(APN), 256, 0, stream>>>(Xap, Xue, W2ap1, W2ap2, adj_ap, ap2ap,
                                                  wap1, wap2, bais_ap,
                                                  out + (size_t)3*UEN*APN);
  k_bn_part       <<<dim3(32), 256, 0, stream>>>(X2ue, part);
  k_bn_final      <<<dim3(1), 256, 0, stream>>>(part, gamma, beta, wue, scsh,
                                                out + (size_t)3*UEN*APN + APN);
  k_bn_apply      <<<dim3(UEN), 256, 0, stream>>>(X2ue, scsh);
  k_ua_head       <<<dim3(UEN/4), 128, 0, stream>>>(X2ue, wue, bais_ue, out);
}

// Round 5
// 585.969 us; speedup vs baseline: 2.4700x; 1.3084x over previous
//
#include <hip/hip_runtime.h>
#include <math.h>
#include <float.h>

// Round 5: green round-4 + factorized UE layer 2 (Ya7/Ya8 -> X2ue self slots,
// Yb8/P7 precomputed into d_out scratch, then gather-assemble). bn_apply folded
// into k_ua_head. ws footprint unchanged vs round 4 (~8.59MB, proven green).

#define APN 105
#define UEN 4000
#define H   128
#define H2  256
#define SS  10
#define INV_NEIGH (1.0f/11.0f)

__device__ __forceinline__ float frelu(float v){ return v > 0.f ? v : 0.f; }

// ---------------- two-hop indices ----------------
__global__ void k_twohop(const int* __restrict__ adj_ue, const int* __restrict__ adj_ap,
                         int* __restrict__ ap2ap, int* __restrict__ ue2ue){
  int idx = blockIdx.x*256 + threadIdx.x;
  if (idx >= (APN+UEN)*SS) return;
  if (idx < APN*SS){
    int s = idx % SS;
    ap2ap[idx] = adj_ue[adj_ap[idx]*SS + s];
  } else {
    int j = idx - APN*SS;
    int s = j % SS;
    ue2ue[j] = adj_ap[adj_ue[j]*SS + s];
  }
}

// ---------------- P3: P3t[n][h] = sum_j W1ue1[h, APN+j]*pl[n, j]  (n<APN) ----------------
__global__ __launch_bounds__(128) void k_p3(
    const float* __restrict__ pl, const float* __restrict__ W1ue1,
    float* __restrict__ P3t)
{
  __shared__ float plrow[UEN];
  int n = blockIdx.x, t = threadIdx.x;
  for (int j=t; j<UEN; j+=128) plrow[j] = pl[(size_t)n*UEN + j];
  __syncthreads();
  const float* w = W1ue1 + (size_t)t*(UEN+APN) + APN;
  float s0=0.f,s1=0.f,s2=0.f,s3=0.f;
  for (int j=0;j<UEN;j+=4){
    s0 = fmaf(w[j  ], plrow[j  ], s0);
    s1 = fmaf(w[j+1], plrow[j+1], s1);
    s2 = fmaf(w[j+2], plrow[j+2], s2);
    s3 = fmaf(w[j+3], plrow[j+3], s3);
  }
  P3t[(size_t)n*H + t] = (s0+s1)+(s2+s3);
}

// ---------------- P7: P7t[n][h] = sum_c W2ue1[h, H2+c]*Xap[n, c]  (n<APN) ----------------
__global__ __launch_bounds__(128) void k_p7(
    const float* __restrict__ Xap, const float* __restrict__ W2ue1,
    float* __restrict__ P7t)
{
  __shared__ float xrow[H2];
  int n = blockIdx.x, t = threadIdx.x;
  xrow[t] = Xap[(size_t)n*H2 + t];
  xrow[t+128] = Xap[(size_t)n*H2 + t + 128];
  __syncthreads();
  const float* w = W2ue1 + (size_t)t*(2*H2) + H2;
  float s0=0.f,s1=0.f,s2=0.f,s3=0.f;
  for (int c=0;c<H2;c+=4){
    s0 = fmaf(w[c  ], xrow[c  ], s0);
    s1 = fmaf(w[c+1], xrow[c+1], s1);
    s2 = fmaf(w[c+2], xrow[c+2], s2);
    s3 = fmaf(w[c+3], xrow[c+3], s3);
  }
  P7t[(size_t)n*H + t] = (s0+s1)+(s2+s3);
}

// ---------------- AP layer 1 (literal, unrolled) ----------------
__global__ __launch_bounds__(256) void k_ap_layer1(
    const float* __restrict__ pl, const float* __restrict__ W1ap1,
    const float* __restrict__ W1ap2, const int* __restrict__ adj_ap,
    const int* __restrict__ ap2ap, float* __restrict__ Xap)
{
  __shared__ float plrow[UEN];
  __shared__ float agg1[112];
  __shared__ float agg2[UEN];
  __shared__ int aj[SS], a2[SS];
  int i = blockIdx.x, t = threadIdx.x;
  if (t < SS){ aj[t] = adj_ap[i*SS+t]; a2[t] = ap2ap[i*SS+t]; }
  __syncthreads();
  for (int j=t; j<UEN; j+=256){
    plrow[j] = pl[(size_t)i*UEN + j];
    float s = 0.f;
    for (int q=0;q<SS;q++) s += pl[(size_t)a2[q]*UEN + j];
    agg2[j] = s*INV_NEIGH;
  }
  if (t < APN){
    float s = 0.f;
    for (int q=0;q<SS;q++) s += pl[(size_t)t*UEN + aj[q]];
    agg1[t] = s*INV_NEIGH;
  }
  __syncthreads();
  float acc;
  if (t < H){
    const float* w = W1ap1 + (size_t)t*(UEN+APN);
    float s0=0.f,s1=0.f,s2=0.f,s3=0.f;
    for (int j=0;j<UEN;j+=4){
      s0 = fmaf(w[j  ], plrow[j  ], s0);
      s1 = fmaf(w[j+1], plrow[j+1], s1);
      s2 = fmaf(w[j+2], plrow[j+2], s2);
      s3 = fmaf(w[j+3], plrow[j+3], s3);
    }
    acc = (s0+s1)+(s2+s3);
    for (int a=0;a<APN;a++) acc = fmaf(w[UEN+a], agg1[a], acc);
  } else {
    const float* w = W1ap2 + (size_t)(t-H)*(2*UEN);
    float s0=0.f,s1=0.f,s2=0.f,s3=0.f;
    for (int j=0;j<UEN;j+=4){
      s0 = fmaf(w[j  ],     plrow[j  ], s0);
      s1 = fmaf(w[j+1],     plrow[j+1], s1);
      s2 = fmaf(w[j+2],     plrow[j+2], s2);
      s3 = fmaf(w[j+3],     plrow[j+3], s3);
    }
    for (int j=0;j<UEN;j+=4){
      s0 = fmaf(w[UEN+j  ], agg2[j  ], s0);
      s1 = fmaf(w[UEN+j+1], agg2[j+1], s1);
      s2 = fmaf(w[UEN+j+2], agg2[j+2], s2);
      s3 = fmaf(w[UEN+j+3], agg2[j+3], s3);
    }
    acc = (s0+s1)+(s2+s3);
  }
  Xap[(size_t)i*H2 + t] = frelu(acc);
}

// ---------------- UE layer 1 v2: x3 via P3 gather; x4 literal ----------------
__global__ __launch_bounds__(256) void k_ue_layer1_v2(
    const float* __restrict__ pl, const float* __restrict__ W1ue1,
    const float* __restrict__ W1ue2, const int* __restrict__ adj_ue,
    const int* __restrict__ ue2ue, const float* __restrict__ P3t,
    float* __restrict__ Xue)
{
  __shared__ float selfr[112];
  __shared__ float agg4[112];
  __shared__ int aj[SS], u2[SS];
  int u = blockIdx.x, t = threadIdx.x;
  if (t < SS){ aj[t] = adj_ue[u*SS+t]; u2[t] = ue2ue[u*SS+t]; }
  __syncthreads();
  if (t < APN){
    selfr[t] = pl[(size_t)t*UEN + u];
    float s = 0.f;
    for (int q=0;q<SS;q++) s += pl[(size_t)t*UEN + u2[q]];
    agg4[t] = s*INV_NEIGH;
  }
  __syncthreads();
  float acc = 0.f;
  if (t < H){
    const float* w = W1ue1 + (size_t)t*(UEN+APN);
    for (int a=0;a<APN;a++) acc = fmaf(w[a], selfr[a], acc);
    float g = 0.f;
    for (int q=0;q<SS;q++) g += P3t[(size_t)aj[q]*H + t];
    acc += g*INV_NEIGH;
  } else {
    const float* w = W1ue2 + (size_t)(t-H)*(2*APN);
    for (int a=0;a<APN;a++) acc = fmaf(w[a],     selfr[a], acc);
    for (int a=0;a<APN;a++) acc = fmaf(w[APN+a], agg4[a],  acc);
  }
  Xue[(size_t)u*H2 + t] = frelu(acc);
}

// ---------------- Family C GEMM: per z-slice, 64-u tile, K=256 ----------------
// z0: X2ue[u][h]      = sum_c W2ue1[h,c]*Xue[u,c]      (Ya7, self slot)
// z1: X2ue[u][128+h]  = sum_c W2ue2[h,c]*Xue[u,c]      (Ya8, self slot)
// z2: Yb8[u][h]       = sum_c W2ue2[h,H2+c]*Xue[u,c]
__global__ __launch_bounds__(256) void k_gemC(
    const float* __restrict__ Xue, const float* __restrict__ W2ue1,
    const float* __restrict__ W2ue2, float* __restrict__ X2ue,
    float* __restrict__ Yb8)
{
  __shared__ float xld[64][H2+1];       // pad 257: bank (u+c)%32, conflict-free
  int u0 = blockIdx.x*64, z = blockIdx.y, t = threadIdx.x;
  for (int e = t; e < 64*H2; e += 256){
    int r = e >> 8, c = e & (H2-1);
    xld[r][c] = (u0+r < UEN) ? Xue[(size_t)(u0+r)*H2 + c] : 0.f;
  }
  __syncthreads();
  int u = t & 63;
  int hbase = __builtin_amdgcn_readfirstlane((t >> 6) * 32);
  const float* W = (z == 0) ? W2ue1 : W2ue2;
  int coff = (z == 2) ? H2 : 0;
  const float* wbase = W + (size_t)hbase*(2*H2) + coff;
  float acc[32];
  #pragma unroll
  for (int h=0;h<32;h++) acc[h] = 0.f;
  for (int c=0;c<H2;c+=4){
    float x0 = xld[u][c], x1 = xld[u][c+1], x2 = xld[u][c+2], x3 = xld[u][c+3];
    #pragma unroll
    for (int h=0;h<32;h++){
      const float* wr = wbase + (size_t)h*(2*H2) + c;
      acc[h] = fmaf(wr[0], x0, fmaf(wr[1], x1, fmaf(wr[2], x2, fmaf(wr[3], x3, acc[h]))));
    }
  }
  if (u0+u < UEN){
    if (z == 0){
      for (int h=0;h<32;h++) X2ue[(size_t)(u0+u)*H2 + hbase + h] = acc[h];
    } else if (z == 1){
      for (int h=0;h<32;h++) X2ue[(size_t)(u0+u)*H2 + H + hbase + h] = acc[h];
    } else {
      for (int h=0;h<32;h++) Yb8[(size_t)(u0+u)*H + hbase + h] = acc[h];
    }
  }
}

// ---------------- x7/x8 assemble: in-place gather + ReLU on X2ue ----------------
__global__ __launch_bounds__(256) void k_x7x8b(
    float* __restrict__ X2ue, const float* __restrict__ P7t,
    const float* __restrict__ Yb8, const int* __restrict__ adj_ue,
    const int* __restrict__ ue2ue)
{
  __shared__ int aj[SS], u2[SS];
  int u = blockIdx.x, t = threadIdx.x;
  if (t < SS){ aj[t] = adj_ue[u*SS+t]; u2[t] = ue2ue[u*SS+t]; }
  __syncthreads();
  float g = X2ue[(size_t)u*H2 + t];
  float s = 0.f;
  if (t < H){
    for (int q=0;q<SS;q++) s += P7t[(size_t)aj[q]*H + t];
  } else {
    for (int q=0;q<SS;q++) s += Yb8[(size_t)u2[q]*H + (t-H)];
  }
  X2ue[(size_t)u*H2 + t] = frelu(g + s*INV_NEIGH);
}

// ---------------- AP layer 2 + PC head (literal, unrolled) ----------------
__global__ __launch_bounds__(256) void k_ap_layer2_head(
    const float* __restrict__ Xap, const float* __restrict__ Xue,
    const float* __restrict__ W2ap1, const float* __restrict__ W2ap2,
    const int* __restrict__ adj_ap, const int* __restrict__ ap2ap,
    const float* __restrict__ wap1, const float* __restrict__ wap2,
    const float* __restrict__ bais_ap, float* __restrict__ out_pc)
{
  __shared__ float xa[H2], a5[H2], a6[H2], xs2[H2], red[256];
  __shared__ int aj[SS], a2i[SS];
  int i = blockIdx.x, t = threadIdx.x;
  if (t < SS){ aj[t] = adj_ap[i*SS+t]; a2i[t] = ap2ap[i*SS+t]; }
  __syncthreads();
  xa[t] = Xap[(size_t)i*H2+t];
  float s5=0.f, s6=0.f;
  for (int q=0;q<SS;q++){
    s5 += Xue[(size_t)aj[q]*H2 + t];
    s6 += Xap[(size_t)a2i[q]*H2 + t];
  }
  a5[t]=s5*INV_NEIGH; a6[t]=s6*INV_NEIGH;
  __syncthreads();
  const float* w; const float* agg;
  if (t < H){ w = W2ap1 + (size_t)t*(2*H2);     agg = a5; }
  else      { w = W2ap2 + (size_t)(t-H)*(2*H2); agg = a6; }
  float s0=0.f,s1=0.f,s2=0.f,s3=0.f;
  for (int c=0;c<H2;c+=4){
    s0 = fmaf(w[c  ], xa[c  ], s0);
    s1 = fmaf(w[c+1], xa[c+1], s1);
    s2 = fmaf(w[c+2], xa[c+2], s2);
    s3 = fmaf(w[c+3], xa[c+3], s3);
  }
  for (int c=0;c<H2;c+=4){
    s0 = fmaf(w[H2+c  ], agg[c  ], s0);
    s1 = fmaf(w[H2+c+1], agg[c+1], s1);
    s2 = fmaf(w[H2+c+2], agg[c+2], s2);
    s3 = fmaf(w[H2+c+3], agg[c+3], s3);
  }
  xs2[t] = frelu((s0+s1)+(s2+s3));
  __syncthreads();
  float hid = bais_ap[i];
  const float* wr1 = wap1 + (size_t)t*H2;
  for (int c=0;c<H2;c++) hid = fmaf(wr1[c], xs2[c], hid);
  red[t] = wap2[t]*hid;
  __syncthreads();
  for (int o=128;o>0;o>>=1){ if (t<o) red[t]+=red[t+o]; __syncthreads(); }
  if (t==0) out_pc[i] = 1.f/(1.f+expf(-red[0]));
}

// ---------------- BatchNorm stats over UEN rows of X2ue ----------------
__global__ __launch_bounds__(256) void k_bn_part(const float* __restrict__ X2ue,
                                                 float* __restrict__ part){
  int b = blockIdx.x, c = threadIdx.x;
  float s=0.f, s2=0.f;
  for (int u = b*125; u < (b+1)*125; u++){
    float v = X2ue[(size_t)u*H2 + c];
    s += v; s2 += v*v;
  }
  part[b*512 + c] = s;
  part[b*512 + 256 + c] = s2;
}

__global__ __launch_bounds__(256) void k_bn_final(
    const float* __restrict__ part, const float* __restrict__ gamma,
    const float* __restrict__ beta, const float* __restrict__ wue,
    float* __restrict__ scsh, float* __restrict__ out_scalar)
{
  __shared__ float red[256];
  int t = threadIdx.x;
  float s=0.f, s2=0.f;
  for (int b=0;b<32;b++){ s += part[b*512+t]; s2 += part[b*512+256+t]; }
  float mean = s*(1.f/UEN);
  float var  = s2*(1.f/UEN) - mean*mean;     // biased, training-mode BN
  float sc = gamma[t]*rsqrtf(var + 1e-5f);
  scsh[t]    = sc;
  scsh[H2+t] = beta[t] - mean*sc;
  float vsum = 0.f;
  if (t < APN){
    const float* wr = wue + (size_t)t*H2;
    float S=0.f, S2=0.f;
    for (int c=0;c<H2;c++){ float w=wr[c]; S+=w; S2+=w*w; }
    vsum = (S2 - S*S*(1.f/H2)) * (1.f/(H2-1));   // ddof=1
  }
  red[t]=vsum; __syncthreads();
  for (int o=128;o>0;o>>=1){ if (t<o) red[t]+=red[t+o]; __syncthreads(); }
  if (t==0) out_scalar[0]=red[0];
}

// ---------------- UA head (BN affine applied on load) ----------------
__global__ __launch_bounds__(128) void k_ua_head(
    const float* __restrict__ X2ue, const float* __restrict__ scsh,
    const float* __restrict__ wue, const float* __restrict__ bais_ue,
    float* __restrict__ out)
{
  __shared__ float xs[4][H2];
  __shared__ float rmax[128], rmin[128], rs1[128], rs2[128];
  int u0 = blockIdx.x*4, t = threadIdx.x;
  #pragma unroll
  for (int q=0;q<4;q++){
    xs[q][t]     = X2ue[(size_t)(u0+q)*H2 + t]*scsh[t] + scsh[H2+t];
    xs[q][t+128] = X2ue[(size_t)(u0+q)*H2 + t + 128]*scsh[t+128] + scsh[H2+t+128];
  }
  __syncthreads();
  int a = t;
  float acc[4] = {0.f,0.f,0.f,0.f};
  if (a < APN){
    const float* wr = wue + (size_t)a*H2;
    for (int c=0;c<H2;c++){
      float w = wr[c];
      acc[0] = fmaf(w, xs[0][c], acc[0]);
      acc[1] = fmaf(w, xs[1][c], acc[1]);
      acc[2] = fmaf(w, xs[2][c], acc[2]);
      acc[3] = fmaf(w, xs[3][c], acc[3]);
    }
    #pragma unroll
    for (int q=0;q<4;q++) acc[q] += bais_ue[u0+q];
  }
  for (int q=0;q<4;q++){
    rmax[t] = (a<APN) ? acc[q] : -FLT_MAX;
    rmin[t] = (a<APN) ? acc[q] :  FLT_MAX;
    __syncthreads();
    for (int o=64;o>0;o>>=1){
      if (t<o){ rmax[t]=fmaxf(rmax[t],rmax[t+o]); rmin[t]=fminf(rmin[t],rmin[t+o]); }
      __syncthreads();
    }
    float mx = rmax[0], mn = rmin[0];
    __syncthreads();
    float nor = (a<APN) ? (acc[q]-mx)/(mx-mn) : 0.f;
    float e1 = (a<APN) ? expf(nor*1000.f) : 0.f;
    float e2 = (a<APN) ? expf(nor)        : 0.f;
    rs1[t]=e1; rs2[t]=e2;
    __syncthreads();
    for (int o=64;o>0;o>>=1){
      if (t<o){ rs1[t]+=rs1[t+o]; rs2[t]+=rs2[t+o]; }
      __syncthreads();
    }
    float s1=rs1[0], s2=rs2[0];
    __syncthreads();
    if (a<APN){
      size_t u = u0+q;
      out[u*APN + a]                     = acc[q];   // UA_ori
      out[(size_t)UEN*APN   + u*APN + a] = e1/s1;    // UA_de
      out[(size_t)2*UEN*APN + u*APN + a] = e2/s2;    // UA_st
    }
  }
}

extern "C" void kernel_launch(void* const* d_in, const int* in_sizes, int n_in,
                              void* d_out, int out_size, void* d_ws, size_t ws_size,
                              hipStream_t stream) {
  const float* pl      = (const float*)d_in[0];
  const int*   adj_ue  = (const int*)d_in[2];
  const int*   adj_ap  = (const int*)d_in[3];
  const float* W1ap1   = (const float*)d_in[4];
  const float* W1ap2   = (const float*)d_in[5];
  const float* W1ue1   = (const float*)d_in[6];
  const float* W1ue2   = (const float*)d_in[7];
  const float* W2ap1   = (const float*)d_in[8];
  const float* W2ap2   = (const float*)d_in[9];
  const float* W2ue1   = (const float*)d_in[10];
  const float* W2ue2   = (const float*)d_in[11];
  const float* wap1    = (const float*)d_in[12];
  const float* wap2    = (const float*)d_in[13];
  const float* bais_ap = (const float*)d_in[14];
  const float* wue     = (const float*)d_in[15];
  const float* bais_ue = (const float*)d_in[16];
  const float* gamma   = (const float*)d_in[17];
  const float* beta    = (const float*)d_in[18];
  float* out = (float*)d_out;
  (void)in_sizes; (void)n_in; (void)out_size; (void)ws_size;

  char* ws = (char*)d_ws;
  size_t off = 0;
  auto alloc = [&](size_t bytes)->char*{
    char* p = ws + off; off += (bytes + 255) & ~(size_t)255; return p;
  };
  int*   ap2ap = (int*)alloc(APN*SS*4);
  int*   ue2ue = (int*)alloc(UEN*SS*4);
  float* Xap   = (float*)alloc((size_t)APN*H2*4);
  float* Xue   = (float*)alloc((size_t)UEN*H2*4);
  float* X2ue  = (float*)alloc((size_t)UEN*H2*4);
  float* part  = (float*)alloc(32*512*4);
  float* scsh  = (float*)alloc(2*H2*4);
  float* P3t   = (float*)alloc((size_t)APN*H*4);
  // d_out scratch (dead before k_ua_head / out_pc / out_scalar writes):
  float* Yb8 = out;                 // [UEN][H] = 512000 floats < 3*UEN*APN
  float* P7t = out + 520000;        // [APN][H] = 13440 floats

  k_twohop        <<<dim3(((APN+UEN)*SS+255)/256), 256, 0, stream>>>(adj_ue, adj_ap, ap2ap, ue2ue);
  k_p3            <<<dim3(APN), 128, 0, stream>>>(pl, W1ue1, P3t);
  k_ap_layer1     <<<dim3(APN), 256, 0, stream>>>(pl, W1ap1, W1ap2, adj_ap, ap2ap, Xap);
  k_ue_layer1_v2  <<<dim3(UEN), 256, 0, stream>>>(pl, W1ue1, W1ue2, adj_ue, ue2ue, P3t, Xue);
  k_p7            <<<dim3(APN), 128, 0, stream>>>(Xap, W2ue1, P7t);
  k_gemC          <<<dim3((UEN+63)/64, 3), 256, 0, stream>>>(Xue, W2ue1, W2ue2, X2ue, Yb8);
  k_ap_layer2_head<<<dim3(APN), 256, 0, stream>>>(Xap, Xue, W2ap1, W2ap2, adj_ap, ap2ap,
                                                  wap1, wap2, bais_ap,
                                                  out + (size_t)3*UEN*APN);
  k_x7x8b         <<<dim3(UEN), 256, 0, stream>>>(X2ue, P7t, Yb8, adj_ue, ue2ue);
  k_bn_part       <<<dim3(32), 256, 0, stream>>>(X2ue, part);
  k_bn_final      <<<dim3(1), 256, 0, stream>>>(part, gamma, beta, wue, scsh,
                                                out + (size_t)3*UEN*APN + APN);
  k_ua_head       <<<dim3(UEN/4), 128, 0, stream>>>(X2ue, scsh, wue, bais_ue, out);
}

// Round 6
// 559.432 us; speedup vs baseline: 2.5872x; 1.0474x over previous
//
#include <hip/hip_runtime.h>
#include <math.h>
#include <float.h>

// Round 6: factorized AP layer 1. All K=4000 slices (G1,G2a,Q2,P3) in one
// K-split GEMM kernel (1680 blocks); U1 fused into ue_layer1; k_x_ap is a
// gather-assemble. New scratch lives in d_out; ws shrinks vs round 5.

#define APN 105
#define UEN 4000
#define H   128
#define H2  256
#define SS  10
#define INV_NEIGH (1.0f/11.0f)

__device__ __forceinline__ float frelu(float v){ return v > 0.f ? v : 0.f; }

// ---------------- two-hop indices ----------------
__global__ void k_twohop(const int* __restrict__ adj_ue, const int* __restrict__ adj_ap,
                         int* __restrict__ ap2ap, int* __restrict__ ue2ue){
  int idx = blockIdx.x*256 + threadIdx.x;
  if (idx >= (APN+UEN)*SS) return;
  if (idx < APN*SS){
    int s = idx % SS;
    ap2ap[idx] = adj_ue[adj_ap[idx]*SS + s];
  } else {
    int j = idx - APN*SS;
    int s = j % SS;
    ue2ue[j] = adj_ap[adj_ue[j]*SS + s];
  }
}

// ---------------- Family A: 4 slices x K-split over K=4000, n<APN ----------------
// slice0 G1 [h][j]=W1ap1[h][j]        slice1 G2a = W1ap2[h][j]
// slice2 Q2 [h][j]=W1ap2[h][UEN+j]    slice3 P3  = W1ue1[h][APN+j]
// partial[(slice*4+ks)][n][h] = sum_{j in ks-range} w[j]*pl[n][j]
__global__ __launch_bounds__(128) void k_gemA4(
    const float* __restrict__ pl, const float* __restrict__ W1ap1,
    const float* __restrict__ W1ap2, const float* __restrict__ W1ue1,
    float* __restrict__ partial)
{
  __shared__ float plrow[1000];
  int n = blockIdx.x, slice = blockIdx.y, ks = blockIdx.z, t = threadIdx.x;
  int k0 = ks*1000;
  for (int j=t; j<1000; j+=128) plrow[j] = pl[(size_t)n*UEN + k0 + j];
  __syncthreads();
  const float* w; int lda;
  if      (slice == 0){ w = W1ap1;       lda = UEN+APN; }
  else if (slice == 1){ w = W1ap2;       lda = 2*UEN;   }
  else if (slice == 2){ w = W1ap2 + UEN; lda = 2*UEN;   }
  else                { w = W1ue1 + APN; lda = UEN+APN; }
  const float* wr = w + (size_t)t*lda + k0;
  float s0=0.f,s1=0.f,s2=0.f,s3=0.f;
  for (int j=0;j<1000;j+=4){
    s0 = fmaf(wr[j  ], plrow[j  ], s0);
    s1 = fmaf(wr[j+1], plrow[j+1], s1);
    s2 = fmaf(wr[j+2], plrow[j+2], s2);
    s3 = fmaf(wr[j+3], plrow[j+3], s3);
  }
  partial[((size_t)(slice*4+ks)*APN + n)*H + t] = (s0+s1)+(s2+s3);
}

// RA[slice][n][h] = sum_ks partial[slice*4+ks][n][h]
__global__ __launch_bounds__(256) void k_redA(const float* __restrict__ partial,
                                              float* __restrict__ RA){
  int idx = blockIdx.x*256 + threadIdx.x;
  if (idx >= 4*APN*H) return;
  int slice = idx / (APN*H), r = idx % (APN*H);
  float s = 0.f;
  #pragma unroll
  for (int ks=0;ks<4;ks++) s += partial[((size_t)(slice*4+ks)*APN*H) + r];
  RA[idx] = s;
}

// ---------------- UE layer 1 + U1: x3 via P3 gather; x4 literal; U1 row ----------------
// U1[u][h] = sum_a W1ap1[h][UEN+a] * pl[a][u]   (x1's agg operand, gathered later)
__global__ __launch_bounds__(256) void k_ue_layer1_v2b(
    const float* __restrict__ pl, const float* __restrict__ W1ap1,
    const float* __restrict__ W1ue1, const float* __restrict__ W1ue2,
    const int* __restrict__ adj_ue, const int* __restrict__ ue2ue,
    const float* __restrict__ P3t, float* __restrict__ Xue,
    float* __restrict__ U1)
{
  __shared__ float selfr[112];
  __shared__ float agg4[112];
  __shared__ int aj[SS], u2[SS];
  int u = blockIdx.x, t = threadIdx.x;
  if (t < SS){ aj[t] = adj_ue[u*SS+t]; u2[t] = ue2ue[u*SS+t]; }
  __syncthreads();
  if (t < APN){
    selfr[t] = pl[(size_t)t*UEN + u];
    float s = 0.f;
    for (int q=0;q<SS;q++) s += pl[(size_t)t*UEN + u2[q]];
    agg4[t] = s*INV_NEIGH;
  }
  __syncthreads();
  float acc = 0.f;
  if (t < H){
    const float* w = W1ue1 + (size_t)t*(UEN+APN);
    for (int a=0;a<APN;a++) acc = fmaf(w[a], selfr[a], acc);
    float g = 0.f;
    for (int q=0;q<SS;q++) g += P3t[(size_t)aj[q]*H + t];
    acc += g*INV_NEIGH;
    // U1 row
    const float* wu = W1ap1 + (size_t)t*(UEN+APN) + UEN;
    float s = 0.f;
    for (int a=0;a<APN;a++) s = fmaf(wu[a], selfr[a], s);
    U1[(size_t)u*H + t] = s;
  } else {
    const float* w = W1ue2 + (size_t)(t-H)*(2*APN);
    for (int a=0;a<APN;a++) acc = fmaf(w[a],     selfr[a], acc);
    for (int a=0;a<APN;a++) acc = fmaf(w[APN+a], agg4[a],  acc);
  }
  Xue[(size_t)u*H2 + t] = frelu(acc);
}

// ---------------- X_ap assemble: x1 = G1 + U1 gather; x2 = G2a + Q2 gather ----------------
__global__ __launch_bounds__(256) void k_x_ap(
    const float* __restrict__ RA, const float* __restrict__ U1,
    const int* __restrict__ adj_ap, const int* __restrict__ ap2ap,
    float* __restrict__ Xap)
{
  __shared__ int aj[SS], a2[SS];
  int i = blockIdx.x, t = threadIdx.x;
  if (t < SS){ aj[t] = adj_ap[i*SS+t]; a2[t] = ap2ap[i*SS+t]; }
  __syncthreads();
  int h = t & (H-1);
  float g, s = 0.f;
  if (t < H){
    g = RA[(size_t)i*H + h];                               // G1
    for (int q=0;q<SS;q++) s += U1[(size_t)aj[q]*H + h];
  } else {
    g = RA[(size_t)APN*H + (size_t)i*H + h];               // G2a
    const float* Q2t = RA + (size_t)2*APN*H;
    for (int q=0;q<SS;q++) s += Q2t[(size_t)a2[q]*H + h];
  }
  Xap[(size_t)i*H2 + t] = frelu(g + s*INV_NEIGH);
}

// ---------------- P7: P7t[n][h] = sum_c W2ue1[h, H2+c]*Xap[n, c]  (n<APN) ----------------
__global__ __launch_bounds__(128) void k_p7(
    const float* __restrict__ Xap, const float* __restrict__ W2ue1,
    float* __restrict__ P7t)
{
  __shared__ float xrow[H2];
  int n = blockIdx.x, t = threadIdx.x;
  xrow[t] = Xap[(size_t)n*H2 + t];
  xrow[t+128] = Xap[(size_t)n*H2 + t + 128];
  __syncthreads();
  const float* w = W2ue1 + (size_t)t*(2*H2) + H2;
  float s0=0.f,s1=0.f,s2=0.f,s3=0.f;
  for (int c=0;c<H2;c+=4){
    s0 = fmaf(w[c  ], xrow[c  ], s0);
    s1 = fmaf(w[c+1], xrow[c+1], s1);
    s2 = fmaf(w[c+2], xrow[c+2], s2);
    s3 = fmaf(w[c+3], xrow[c+3], s3);
  }
  P7t[(size_t)n*H + t] = (s0+s1)+(s2+s3);
}

// ---------------- Family C GEMM: per z-slice, 64-u tile, K=256 ----------------
__global__ __launch_bounds__(256) void k_gemC(
    const float* __restrict__ Xue, const float* __restrict__ W2ue1,
    const float* __restrict__ W2ue2, float* __restrict__ X2ue,
    float* __restrict__ Yb8)
{
  __shared__ float xld[64][H2+1];
  int u0 = blockIdx.x*64, z = blockIdx.y, t = threadIdx.x;
  for (int e = t; e < 64*H2; e += 256){
    int r = e >> 8, c = e & (H2-1);
    xld[r][c] = (u0+r < UEN) ? Xue[(size_t)(u0+r)*H2 + c] : 0.f;
  }
  __syncthreads();
  int u = t & 63;
  int hbase = __builtin_amdgcn_readfirstlane((t >> 6) * 32);
  const float* W = (z == 0) ? W2ue1 : W2ue2;
  int coff = (z == 2) ? H2 : 0;
  const float* wbase = W + (size_t)hbase*(2*H2) + coff;
  float acc[32];
  #pragma unroll
  for (int h=0;h<32;h++) acc[h] = 0.f;
  for (int c=0;c<H2;c+=4){
    float x0 = xld[u][c], x1 = xld[u][c+1], x2 = xld[u][c+2], x3 = xld[u][c+3];
    #pragma unroll
    for (int h=0;h<32;h++){
      const float* wr = wbase + (size_t)h*(2*H2) + c;
      acc[h] = fmaf(wr[0], x0, fmaf(wr[1], x1, fmaf(wr[2], x2, fmaf(wr[3], x3, acc[h]))));
    }
  }
  if (u0+u < UEN){
    if (z == 0){
      for (int h=0;h<32;h++) X2ue[(size_t)(u0+u)*H2 + hbase + h] = acc[h];
    } else if (z == 1){
      for (int h=0;h<32;h++) X2ue[(size_t)(u0+u)*H2 + H + hbase + h] = acc[h];
    } else {
      for (int h=0;h<32;h++) Yb8[(size_t)(u0+u)*H + hbase + h] = acc[h];
    }
  }
}

// ---------------- x7/x8 assemble: in-place gather + ReLU on X2ue ----------------
__global__ __launch_bounds__(256) void k_x7x8b(
    float* __restrict__ X2ue, const float* __restrict__ P7t,
    const float* __restrict__ Yb8, const int* __restrict__ adj_ue,
    const int* __restrict__ ue2ue)
{
  __shared__ int aj[SS], u2[SS];
  int u = blockIdx.x, t = threadIdx.x;
  if (t < SS){ aj[t] = adj_ue[u*SS+t]; u2[t] = ue2ue[u*SS+t]; }
  __syncthreads();
  float g = X2ue[(size_t)u*H2 + t];
  float s = 0.f;
  if (t < H){
    for (int q=0;q<SS;q++) s += P7t[(size_t)aj[q]*H + t];
  } else {
    for (int q=0;q<SS;q++) s += Yb8[(size_t)u2[q]*H + (t-H)];
  }
  X2ue[(size_t)u*H2 + t] = frelu(g + s*INV_NEIGH);
}

// ---------------- AP layer 2 + PC head ----------------
__global__ __launch_bounds__(256) void k_ap_layer2_head(
    const float* __restrict__ Xap, const float* __restrict__ Xue,
    const float* __restrict__ W2ap1, const float* __restrict__ W2ap2,
    const int* __restrict__ adj_ap, const int* __restrict__ ap2ap,
    const float* __restrict__ wap1, const float* __restrict__ wap2,
    const float* __restrict__ bais_ap, float* __restrict__ out_pc)
{
  __shared__ float xa[H2], a5[H2], a6[H2], xs2[H2], red[256];
  __shared__ int aj[SS], a2i[SS];
  int i = blockIdx.x, t = threadIdx.x;
  if (t < SS){ aj[t] = adj_ap[i*SS+t]; a2i[t] = ap2ap[i*SS+t]; }
  __syncthreads();
  xa[t] = Xap[(size_t)i*H2+t];
  float s5=0.f, s6=0.f;
  for (int q=0;q<SS;q++){
    s5 += Xue[(size_t)aj[q]*H2 + t];
    s6 += Xap[(size_t)a2i[q]*H2 + t];
  }
  a5[t]=s5*INV_NEIGH; a6[t]=s6*INV_NEIGH;
  __syncthreads();
  const float* w; const float* agg;
  if (t < H){ w = W2ap1 + (size_t)t*(2*H2);     agg = a5; }
  else      { w = W2ap2 + (size_t)(t-H)*(2*H2); agg = a6; }
  float s0=0.f,s1=0.f,s2=0.f,s3=0.f;
  for (int c=0;c<H2;c+=4){
    s0 = fmaf(w[c  ], xa[c  ], s0);
    s1 = fmaf(w[c+1], xa[c+1], s1);
    s2 = fmaf(w[c+2], xa[c+2], s2);
    s3 = fmaf(w[c+3], xa[c+3], s3);
  }
  for (int c=0;c<H2;c+=4){
    s0 = fmaf(w[H2+c  ], agg[c  ], s0);
    s1 = fmaf(w[H2+c+1], agg[c+1], s1);
    s2 = fmaf(w[H2+c+2], agg[c+2], s2);
    s3 = fmaf(w[H2+c+3], agg[c+3], s3);
  }
  xs2[t] = frelu((s0+s1)+(s2+s3));
  __syncthreads();
  float hid = bais_ap[i];
  const float* wr1 = wap1 + (size_t)t*H2;
  for (int c=0;c<H2;c++) hid = fmaf(wr1[c], xs2[c], hid);
  red[t] = wap2[t]*hid;
  __syncthreads();
  for (int o=128;o>0;o>>=1){ if (t<o) red[t]+=red[t+o]; __syncthreads(); }
  if (t==0) out_pc[i] = 1.f/(1.f+expf(-red[0]));
}

// ---------------- BatchNorm stats ----------------
__global__ __launch_bounds__(256) void k_bn_part(const float* __restrict__ X2ue,
                                                 float* __restrict__ part){
  int b = blockIdx.x, c = threadIdx.x;
  float s=0.f, s2=0.f;
  for (int u = b*125; u < (b+1)*125; u++){
    float v = X2ue[(size_t)u*H2 + c];
    s += v; s2 += v*v;
  }
  part[b*512 + c] = s;
  part[b*512 + 256 + c] = s2;
}

__global__ __launch_bounds__(256) void k_bn_final(
    const float* __restrict__ part, const float* __restrict__ gamma,
    const float* __restrict__ beta, const float* __restrict__ wue,
    float* __restrict__ scsh, float* __restrict__ out_scalar)
{
  __shared__ float red[256];
  int t = threadIdx.x;
  float s=0.f, s2=0.f;
  for (int b=0;b<32;b++){ s += part[b*512+t]; s2 += part[b*512+256+t]; }
  float mean = s*(1.f/UEN);
  float var  = s2*(1.f/UEN) - mean*mean;
  float sc = gamma[t]*rsqrtf(var + 1e-5f);
  scsh[t]    = sc;
  scsh[H2+t] = beta[t] - mean*sc;
  float vsum = 0.f;
  if (t < APN){
    const float* wr = wue + (size_t)t*H2;
    float S=0.f, S2=0.f;
    for (int c=0;c<H2;c++){ float w=wr[c]; S+=w; S2+=w*w; }
    vsum = (S2 - S*S*(1.f/H2)) * (1.f/(H2-1));
  }
  red[t]=vsum; __syncthreads();
  for (int o=128;o>0;o>>=1){ if (t<o) red[t]+=red[t+o]; __syncthreads(); }
  if (t==0) out_scalar[0]=red[0];
}

// ---------------- UA head (BN affine on load) ----------------
__global__ __launch_bounds__(128) void k_ua_head(
    const float* __restrict__ X2ue, const float* __restrict__ scsh,
    const float* __restrict__ wue, const float* __restrict__ bais_ue,
    float* __restrict__ out)
{
  __shared__ float xs[4][H2];
  __shared__ float rmax[128], rmin[128], rs1[128], rs2[128];
  int u0 = blockIdx.x*4, t = threadIdx.x;
  #pragma unroll
  for (int q=0;q<4;q++){
    xs[q][t]     = X2ue[(size_t)(u0+q)*H2 + t]*scsh[t] + scsh[H2+t];
    xs[q][t+128] = X2ue[(size_t)(u0+q)*H2 + t + 128]*scsh[t+128] + scsh[H2+t+128];
  }
  __syncthreads();
  int a = t;
  float acc[4] = {0.f,0.f,0.f,0.f};
  if (a < APN){
    const float* wr = wue + (size_t)a*H2;
    for (int c=0;c<H2;c++){
      float w = wr[c];
      acc[0] = fmaf(w, xs[0][c], acc[0]);
      acc[1] = fmaf(w, xs[1][c], acc[1]);
      acc[2] = fmaf(w, xs[2][c], acc[2]);
      acc[3] = fmaf(w, xs[3][c], acc[3]);
    }
    #pragma unroll
    for (int q=0;q<4;q++) acc[q] += bais_ue[u0+q];
  }
  for (int q=0;q<4;q++){
    rmax[t] = (a<APN) ? acc[q] : -FLT_MAX;
    rmin[t] = (a<APN) ? acc[q] :  FLT_MAX;
    __syncthreads();
    for (int o=64;o>0;o>>=1){
      if (t<o){ rmax[t]=fmaxf(rmax[t],rmax[t+o]); rmin[t]=fminf(rmin[t],rmin[t+o]); }
      __syncthreads();
    }
    float mx = rmax[0], mn = rmin[0];
    __syncthreads();
    float nor = (a<APN) ? (acc[q]-mx)/(mx-mn) : 0.f;
    float e1 = (a<APN) ? expf(nor*1000.f) : 0.f;
    float e2 = (a<APN) ? expf(nor)        : 0.f;
    rs1[t]=e1; rs2[t]=e2;
    __syncthreads();
    for (int o=64;o>0;o>>=1){
      if (t<o){ rs1[t]+=rs1[t+o]; rs2[t]+=rs2[t+o]; }
      __syncthreads();
    }
    float s1=rs1[0], s2=rs2[0];
    __syncthreads();
    if (a<APN){
      size_t u = u0+q;
      out[u*APN + a]                     = acc[q];   // UA_ori
      out[(size_t)UEN*APN   + u*APN + a] = e1/s1;    // UA_de
      out[(size_t)2*UEN*APN + u*APN + a] = e2/s2;    // UA_st
    }
  }
}

extern "C" void kernel_launch(void* const* d_in, const int* in_sizes, int n_in,
                              void* d_out, int out_size, void* d_ws, size_t ws_size,
                              hipStream_t stream) {
  const float* pl      = (const float*)d_in[0];
  const int*   adj_ue  = (const int*)d_in[2];
  const int*   adj_ap  = (const int*)d_in[3];
  const float* W1ap1   = (const float*)d_in[4];
  const float* W1ap2   = (const float*)d_in[5];
  const float* W1ue1   = (const float*)d_in[6];
  const float* W1ue2   = (const float*)d_in[7];
  const float* W2ap1   = (const float*)d_in[8];
  const float* W2ap2   = (const float*)d_in[9];
  const float* W2ue1   = (const float*)d_in[10];
  const float* W2ue2   = (const float*)d_in[11];
  const float* wap1    = (const float*)d_in[12];
  const float* wap2    = (const float*)d_in[13];
  const float* bais_ap = (const float*)d_in[14];
  const float* wue     = (const float*)d_in[15];
  const float* bais_ue = (const float*)d_in[16];
  const float* gamma   = (const float*)d_in[17];
  const float* beta    = (const float*)d_in[18];
  float* out = (float*)d_out;
  (void)in_sizes; (void)n_in; (void)out_size; (void)ws_size;

  char* ws = (char*)d_ws;
  size_t off = 0;
  auto alloc = [&](size_t bytes)->char*{
    char* p = ws + off; off += (bytes + 255) & ~(size_t)255; return p;
  };
  int*   ap2ap = (int*)alloc(APN*SS*4);
  int*   ue2ue = (int*)alloc(UEN*SS*4);
  float* Xap   = (float*)alloc((size_t)APN*H2*4);
  float* Xue   = (float*)alloc((size_t)UEN*H2*4);
  float* X2ue  = (float*)alloc((size_t)UEN*H2*4);
  float* part  = (float*)alloc(32*512*4);
  float* scsh  = (float*)alloc(2*H2*4);
  // d_out scratch map (floats; out_size = 1,260,106):
  //  [0      .. 512,000)  U1  (phase A)  ->  Yb8 (phase B, after U1 dead)
  //  [520,000.. 533,440)  P7t
  //  [600,000.. 815,040)  gemA partials (16 x 105 x 128)
  //  [850,000..1,065,040) RA (4 x 105 x 128): G1,G2a,Q2,P3
  // Final kernels overwrite all of d_out afterwards.
  float* U1      = out;
  float* Yb8     = out;
  float* P7t     = out + 520000;
  float* partialA= out + 600000;
  float* RA      = out + 850000;
  float* P3t     = RA + (size_t)3*APN*H;

  k_twohop        <<<dim3(((APN+UEN)*SS+255)/256), 256, 0, stream>>>(adj_ue, adj_ap, ap2ap, ue2ue);
  k_gemA4         <<<dim3(APN,4,4), 128, 0, stream>>>(pl, W1ap1, W1ap2, W1ue1, partialA);
  k_redA          <<<dim3((4*APN*H+255)/256), 256, 0, stream>>>(partialA, RA);
  k_ue_layer1_v2b <<<dim3(UEN), 256, 0, stream>>>(pl, W1ap1, W1ue1, W1ue2, adj_ue, ue2ue,
                                                  P3t, Xue, U1);
  k_x_ap          <<<dim3(APN), 256, 0, stream>>>(RA, U1, adj_ap, ap2ap, Xap);
  k_p7            <<<dim3(APN), 128, 0, stream>>>(Xap, W2ue1, P7t);
  k_gemC          <<<dim3((UEN+63)/64, 3), 256, 0, stream>>>(Xue, W2ue1, W2ue2, X2ue, Yb8);
  k_ap_layer2_head<<<dim3(APN), 256, 0, stream>>>(Xap, Xue, W2ap1, W2ap2, adj_ap, ap2ap,
                                                  wap1, wap2, bais_ap,
                                                  out + (size_t)3*UEN*APN);
  k_x7x8b         <<<dim3(UEN), 256, 0, stream>>>(X2ue, P7t, Yb8, adj_ue, ue2ue);
  k_bn_part       <<<dim3(32), 256, 0, stream>>>(X2ue, part);
  k_bn_final      <<<dim3(1), 256, 0, stream>>>(part, gamma, beta, wue, scsh,
                                                out + (size_t)3*UEN*APN + APN);
  k_ua_head       <<<dim3(UEN/4), 128, 0, stream>>>(X2ue, scsh, wue, bais_ue, out);
}

// Round 8
// 432.701 us; speedup vs baseline: 3.3449x; 1.2929x over previous
//
#include <hip/hip_runtime.h>
#include <math.h>
#include <float.h>

// Round 8 (= round 7 resubmitted after GPU-acquisition timeout; no result yet):
// family-B factorized (T3/T4/R4/U1 as one tiled GEMM over K=105);
// Xue assembly is a pure gather kernel. Scratch: T3/T4 in X2ue ws buffer,
// partials in Xue ws buffer, U1/R4/RA/P7t in d_out. ws footprint = round 6.

#define APN 105
#define UEN 4000
#define H   128
#define H2  256
#define SS  10
#define INV_NEIGH (1.0f/11.0f)

__device__ __forceinline__ float frelu(float v){ return v > 0.f ? v : 0.f; }

// ---------------- two-hop indices ----------------
__global__ void k_twohop(const int* __restrict__ adj_ue, const int* __restrict__ adj_ap,
                         int* __restrict__ ap2ap, int* __restrict__ ue2ue){
  int idx = blockIdx.x*256 + threadIdx.x;
  if (idx >= (APN+UEN)*SS) return;
  if (idx < APN*SS){
    int s = idx % SS;
    ap2ap[idx] = adj_ue[adj_ap[idx]*SS + s];
  } else {
    int j = idx - APN*SS;
    int s = j % SS;
    ue2ue[j] = adj_ap[adj_ue[j]*SS + s];
  }
}

// ---------------- Family A: 4 slices x 4 K-splits over K=4000, n<APN ----------------
// slice0 G1 = W1ap1[:, :4000]   slice1 G2a = W1ap2[:, :4000]
// slice2 Q2 = W1ap2[:, 4000:]   slice3 P3  = W1ue1[:, 105:]
__global__ __launch_bounds__(128) void k_gemA4(
    const float* __restrict__ pl, const float* __restrict__ W1ap1,
    const float* __restrict__ W1ap2, const float* __restrict__ W1ue1,
    float* __restrict__ partial)
{
  __shared__ float plrow[1000];
  int n = blockIdx.x, slice = blockIdx.y, ks = blockIdx.z, t = threadIdx.x;
  int k0 = ks*1000;
  for (int j=t; j<1000; j+=128) plrow[j] = pl[(size_t)n*UEN + k0 + j];
  __syncthreads();
  const float* w; int lda;
  if      (slice == 0){ w = W1ap1;       lda = UEN+APN; }
  else if (slice == 1){ w = W1ap2;       lda = 2*UEN;   }
  else if (slice == 2){ w = W1ap2 + UEN; lda = 2*UEN;   }
  else                { w = W1ue1 + APN; lda = UEN+APN; }
  const float* wr = w + (size_t)t*lda + k0;
  float s0=0.f,s1=0.f,s2=0.f,s3=0.f;
  for (int j=0;j<1000;j+=4){
    s0 = fmaf(wr[j  ], plrow[j  ], s0);
    s1 = fmaf(wr[j+1], plrow[j+1], s1);
    s2 = fmaf(wr[j+2], plrow[j+2], s2);
    s3 = fmaf(wr[j+3], plrow[j+3], s3);
  }
  partial[((size_t)(slice*4+ks)*APN + n)*H + t] = (s0+s1)+(s2+s3);
}

__global__ __launch_bounds__(256) void k_redA(const float* __restrict__ partial,
                                              float* __restrict__ RA){
  int idx = blockIdx.x*256 + threadIdx.x;
  if (idx >= 4*APN*H) return;
  int slice = idx / (APN*H), r = idx % (APN*H);
  float s = 0.f;
  #pragma unroll
  for (int ks=0;ks<4;ks++) s += partial[((size_t)(slice*4+ks)*APN*H) + r];
  RA[idx] = s;
}

// ---------------- Family B: 4 slices over K=105, n<UEN ----------------
// z0 T3 = W1ue1[:, :105] @ pl    z1 T4 = W1ue2[:, :105] @ pl
// z2 U1 = W1ap1[:, 4000:] @ pl   z3 R4 = W1ue2[:, 105:] @ pl
// out[n][h], row-major per slice.
__global__ __launch_bounds__(256) void k_gemB(
    const float* __restrict__ pl, const float* __restrict__ W1ap1,
    const float* __restrict__ W1ue1, const float* __restrict__ W1ue2,
    float* __restrict__ T3, float* __restrict__ T4,
    float* __restrict__ U1, float* __restrict__ R4)
{
  __shared__ float xld[105][72];       // [a][u], 30.2KB
  int u0 = blockIdx.x*64, z = blockIdx.y, t = threadIdx.x;
  for (int e = t; e < 105*64; e += 256){
    int a = e >> 6, u = e & 63;
    xld[a][u] = (u0+u < UEN) ? pl[(size_t)a*UEN + u0 + u] : 0.f;
  }
  __syncthreads();
  int u = t & 63;
  int hbase = __builtin_amdgcn_readfirstlane((t >> 6) * 32);
  const float* w; int lda; float* outp;
  if      (z == 0){ w = W1ue1;       lda = UEN+APN; outp = T3; }
  else if (z == 1){ w = W1ue2;       lda = 2*APN;   outp = T4; }
  else if (z == 2){ w = W1ap1 + UEN; lda = UEN+APN; outp = U1; }
  else            { w = W1ue2 + APN; lda = 2*APN;   outp = R4; }
  const float* wbase = w + (size_t)hbase*lda;
  float acc[32];
  #pragma unroll
  for (int h=0;h<32;h++) acc[h] = 0.f;
  int a = 0;
  for (; a+3 < 105; a += 4){
    float x0 = xld[a][u], x1 = xld[a+1][u], x2 = xld[a+2][u], x3 = xld[a+3][u];
    #pragma unroll
    for (int h=0;h<32;h++){
      const float* wr = wbase + (size_t)h*lda + a;
      acc[h] = fmaf(wr[0], x0, fmaf(wr[1], x1, fmaf(wr[2], x2, fmaf(wr[3], x3, acc[h]))));
    }
  }
  {   // a = 104 tail
    float x0 = xld[104][u];
    #pragma unroll
    for (int h=0;h<32;h++) acc[h] = fmaf(wbase[(size_t)h*lda + 104], x0, acc[h]);
  }
  if (u0+u < UEN){
    for (int h=0;h<32;h++) outp[(size_t)(u0+u)*H + hbase + h] = acc[h];
  }
}

// ---------------- Xue assemble: x3 = T3 + P3 gather; x4 = T4 + R4 gather ----------------
__global__ __launch_bounds__(256) void k_x_ueB(
    const float* __restrict__ T3, const float* __restrict__ T4,
    const float* __restrict__ P3t, const float* __restrict__ R4,
    const int* __restrict__ adj_ue, const int* __restrict__ ue2ue,
    float* __restrict__ Xue)
{
  __shared__ int aj[SS], u2[SS];
  int u = blockIdx.x, t = threadIdx.x;
  if (t < SS){ aj[t] = adj_ue[u*SS+t]; u2[t] = ue2ue[u*SS+t]; }
  __syncthreads();
  int h = t & (H-1);
  float g, s = 0.f;
  if (t < H){
    g = T3[(size_t)u*H + h];
    for (int q=0;q<SS;q++) s += P3t[(size_t)aj[q]*H + h];
  } else {
    g = T4[(size_t)u*H + h];
    for (int q=0;q<SS;q++) s += R4[(size_t)u2[q]*H + h];
  }
  Xue[(size_t)u*H2 + t] = frelu(g + s*INV_NEIGH);
}

// ---------------- X_ap assemble ----------------
__global__ __launch_bounds__(256) void k_x_ap(
    const float* __restrict__ RA, const float* __restrict__ U1,
    const int* __restrict__ adj_ap, const int* __restrict__ ap2ap,
    float* __restrict__ Xap)
{
  __shared__ int aj[SS], a2[SS];
  int i = blockIdx.x, t = threadIdx.x;
  if (t < SS){ aj[t] = adj_ap[i*SS+t]; a2[t] = ap2ap[i*SS+t]; }
  __syncthreads();
  int h = t & (H-1);
  float g, s = 0.f;
  if (t < H){
    g = RA[(size_t)i*H + h];                               // G1
    for (int q=0;q<SS;q++) s += U1[(size_t)aj[q]*H + h];
  } else {
    g = RA[(size_t)APN*H + (size_t)i*H + h];               // G2a
    const float* Q2t = RA + (size_t)2*APN*H;
    for (int q=0;q<SS;q++) s += Q2t[(size_t)a2[q]*H + h];
  }
  Xap[(size_t)i*H2 + t] = frelu(g + s*INV_NEIGH);
}

// ---------------- P7 ----------------
__global__ __launch_bounds__(128) void k_p7(
    const float* __restrict__ Xap, const float* __restrict__ W2ue1,
    float* __restrict__ P7t)
{
  __shared__ float xrow[H2];
  int n = blockIdx.x, t = threadIdx.x;
  xrow[t] = Xap[(size_t)n*H2 + t];
  xrow[t+128] = Xap[(size_t)n*H2 + t + 128];
  __syncthreads();
  const float* w = W2ue1 + (size_t)t*(2*H2) + H2;
  float s0=0.f,s1=0.f,s2=0.f,s3=0.f;
  for (int c=0;c<H2;c+=4){
    s0 = fmaf(w[c  ], xrow[c  ], s0);
    s1 = fmaf(w[c+1], xrow[c+1], s1);
    s2 = fmaf(w[c+2], xrow[c+2], s2);
    s3 = fmaf(w[c+3], xrow[c+3], s3);
  }
  P7t[(size_t)n*H + t] = (s0+s1)+(s2+s3);
}

// ---------------- Family C GEMM ----------------
__global__ __launch_bounds__(256) void k_gemC(
    const float* __restrict__ Xue, const float* __restrict__ W2ue1,
    const float* __restrict__ W2ue2, float* __restrict__ X2ue,
    float* __restrict__ Yb8)
{
  __shared__ float xld[64][H2+1];
  int u0 = blockIdx.x*64, z = blockIdx.y, t = threadIdx.x;
  for (int e = t; e < 64*H2; e += 256){
    int r = e >> 8, c = e & (H2-1);
    xld[r][c] = (u0+r < UEN) ? Xue[(size_t)(u0+r)*H2 + c] : 0.f;
  }
  __syncthreads();
  int u = t & 63;
  int hbase = __builtin_amdgcn_readfirstlane((t >> 6) * 32);
  const float* W = (z == 0) ? W2ue1 : W2ue2;
  int coff = (z == 2) ? H2 : 0;
  const float* wbase = W + (size_t)hbase*(2*H2) + coff;
  float acc[32];
  #pragma unroll
  for (int h=0;h<32;h++) acc[h] = 0.f;
  for (int c=0;c<H2;c+=4){
    float x0 = xld[u][c], x1 = xld[u][c+1], x2 = xld[u][c+2], x3 = xld[u][c+3];
    #pragma unroll
    for (int h=0;h<32;h++){
      const float* wr = wbase + (size_t)h*(2*H2) + c;
      acc[h] = fmaf(wr[0], x0, fmaf(wr[1], x1, fmaf(wr[2], x2, fmaf(wr[3], x3, acc[h]))));
    }
  }
  if (u0+u < UEN){
    if (z == 0){
      for (int h=0;h<32;h++) X2ue[(size_t)(u0+u)*H2 + hbase + h] = acc[h];
    } else if (z == 1){
      for (int h=0;h<32;h++) X2ue[(size_t)(u0+u)*H2 + H + hbase + h] = acc[h];
    } else {
      for (int h=0;h<32;h++) Yb8[(size_t)(u0+u)*H + hbase + h] = acc[h];
    }
  }
}

// ---------------- x7/x8 assemble ----------------
__global__ __launch_bounds__(256) void k_x7x8b(
    float* __restrict__ X2ue, const float* __restrict__ P7t,
    const float* __restrict__ Yb8, const int* __restrict__ adj_ue,
    const int* __restrict__ ue2ue)
{
  __shared__ int aj[SS], u2[SS];
  int u = blockIdx.x, t = threadIdx.x;
  if (t < SS){ aj[t] = adj_ue[u*SS+t]; u2[t] = ue2ue[u*SS+t]; }
  __syncthreads();
  float g = X2ue[(size_t)u*H2 + t];
  float s = 0.f;
  if (t < H){
    for (int q=0;q<SS;q++) s += P7t[(size_t)aj[q]*H + t];
  } else {
    for (int q=0;q<SS;q++) s += Yb8[(size_t)u2[q]*H + (t-H)];
  }
  X2ue[(size_t)u*H2 + t] = frelu(g + s*INV_NEIGH);
}

// ---------------- AP layer 2 + PC head ----------------
__global__ __launch_bounds__(256) void k_ap_layer2_head(
    const float* __restrict__ Xap, const float* __restrict__ Xue,
    const float* __restrict__ W2ap1, const float* __restrict__ W2ap2,
    const int* __restrict__ adj_ap, const int* __restrict__ ap2ap,
    const float* __restrict__ wap1, const float* __restrict__ wap2,
    const float* __restrict__ bais_ap, float* __restrict__ out_pc)
{
  __shared__ float xa[H2], a5[H2], a6[H2], xs2[H2], red[256];
  __shared__ int aj[SS], a2i[SS];
  int i = blockIdx.x, t = threadIdx.x;
  if (t < SS){ aj[t] = adj_ap[i*SS+t]; a2i[t] = ap2ap[i*SS+t]; }
  __syncthreads();
  xa[t] = Xap[(size_t)i*H2+t];
  float s5=0.f, s6=0.f;
  for (int q=0;q<SS;q++){
    s5 += Xue[(size_t)aj[q]*H2 + t];
    s6 += Xap[(size_t)a2i[q]*H2 + t];
  }
  a5[t]=s5*INV_NEIGH; a6[t]=s6*INV_NEIGH;
  __syncthreads();
  const float* w; const float* agg;
  if (t < H){ w = W2ap1 + (size_t)t*(2*H2);     agg = a5; }
  else      { w = W2ap2 + (size_t)(t-H)*(2*H2); agg = a6; }
  float s0=0.f,s1=0.f,s2=0.f,s3=0.f;
  for (int c=0;c<H2;c+=4){
    s0 = fmaf(w[c  ], xa[c  ], s0);
    s1 = fmaf(w[c+1], xa[c+1], s1);
    s2 = fmaf(w[c+2], xa[c+2], s2);
    s3 = fmaf(w[c+3], xa[c+3], s3);
  }
  for (int c=0;c<H2;c+=4){
    s0 = fmaf(w[H2+c  ], agg[c  ], s0);
    s1 = fmaf(w[H2+c+1], agg[c+1], s1);
    s2 = fmaf(w[H2+c+2], agg[c+2], s2);
    s3 = fmaf(w[H2+c+3], agg[c+3], s3);
  }
  xs2[t] = frelu((s0+s1)+(s2+s3));
  __syncthreads();
  float hid = bais_ap[i];
  const float* wr1 = wap1 + (size_t)t*H2;
  for (int c=0;c<H2;c++) hid = fmaf(wr1[c], xs2[c], hid);
  red[t] = wap2[t]*hid;
  __syncthreads();
  for (int o=128;o>0;o>>=1){ if (t<o) red[t]+=red[t+o]; __syncthreads(); }
  if (t==0) out_pc[i] = 1.f/(1.f+expf(-red[0]));
}

// ---------------- BatchNorm ----------------
__global__ __launch_bounds__(256) void k_bn_part(const float* __restrict__ X2ue,
                                                 float* __restrict__ part){
  int b = blockIdx.x, c = threadIdx.x;
  float s=0.f, s2=0.f;
  for (int u = b*125; u < (b+1)*125; u++){
    float v = X2ue[(size_t)u*H2 + c];
    s += v; s2 += v*v;
  }
  part[b*512 + c] = s;
  part[b*512 + 256 + c] = s2;
}

__global__ __launch_bounds__(256) void k_bn_final(
    const float* __restrict__ part, const float* __restrict__ gamma,
    const float* __restrict__ beta, const float* __restrict__ wue,
    float* __restrict__ scsh, float* __restrict__ out_scalar)
{
  __shared__ float red[256];
  int t = threadIdx.x;
  float s=0.f, s2=0.f;
  for (int b=0;b<32;b++){ s += part[b*512+t]; s2 += part[b*512+256+t]; }
  float mean = s*(1.f/UEN);
  float var  = s2*(1.f/UEN) - mean*mean;
  float sc = gamma[t]*rsqrtf(var + 1e-5f);
  scsh[t]    = sc;
  scsh[H2+t] = beta[t] - mean*sc;
  float vsum = 0.f;
  if (t < APN){
    const float* wr = wue + (size_t)t*H2;
    float S=0.f, S2=0.f;
    for (int c=0;c<H2;c++){ float w=wr[c]; S+=w; S2+=w*w; }
    vsum = (S2 - S*S*(1.f/H2)) * (1.f/(H2-1));
  }
  red[t]=vsum; __syncthreads();
  for (int o=128;o>0;o>>=1){ if (t<o) red[t]+=red[t+o]; __syncthreads(); }
  if (t==0) out_scalar[0]=red[0];
}

// ---------------- UA head (BN affine on load) ----------------
__global__ __launch_bounds__(128) void k_ua_head(
    const float* __restrict__ X2ue, const float* __restrict__ scsh,
    const float* __restrict__ wue, const float* __restrict__ bais_ue,
    float* __restrict__ out)
{
  __shared__ float xs[4][H2];
  __shared__ float rmax[128], rmin[128], rs1[128], rs2[128];
  int u0 = blockIdx.x*4, t = threadIdx.x;
  #pragma unroll
  for (int q=0;q<4;q++){
    xs[q][t]     = X2ue[(size_t)(u0+q)*H2 + t]*scsh[t] + scsh[H2+t];
    xs[q][t+128] = X2ue[(size_t)(u0+q)*H2 + t + 128]*scsh[t+128] + scsh[H2+t+128];
  }
  __syncthreads();
  int a = t;
  float acc[4] = {0.f,0.f,0.f,0.f};
  if (a < APN){
    const float* wr = wue + (size_t)a*H2;
    for (int c=0;c<H2;c++){
      float w = wr[c];
      acc[0] = fmaf(w, xs[0][c], acc[0]);
      acc[1] = fmaf(w, xs[1][c], acc[1]);
      acc[2] = fmaf(w, xs[2][c], acc[2]);
      acc[3] = fmaf(w, xs[3][c], acc[3]);
    }
    #pragma unroll
    for (int q=0;q<4;q++) acc[q] += bais_ue[u0+q];
  }
  for (int q=0;q<4;q++){
    rmax[t] = (a<APN) ? acc[q] : -FLT_MAX;
    rmin[t] = (a<APN) ? acc[q] :  FLT_MAX;
    __syncthreads();
    for (int o=64;o>0;o>>=1){
      if (t<o){ rmax[t]=fmaxf(rmax[t],rmax[t+o]); rmin[t]=fminf(rmin[t],rmin[t+o]); }
      __syncthreads();
    }
    float mx = rmax[0], mn = rmin[0];
    __syncthreads();
    float nor = (a<APN) ? (acc[q]-mx)/(mx-mn) : 0.f;
    float e1 = (a<APN) ? expf(nor*1000.f) : 0.f;
    float e2 = (a<APN) ? expf(nor)        : 0.f;
    rs1[t]=e1; rs2[t]=e2;
    __syncthreads();
    for (int o=64;o>0;o>>=1){
      if (t<o){ rs1[t]+=rs1[t+o]; rs2[t]+=rs2[t+o]; }
      __syncthreads();
    }
    float s1=rs1[0], s2=rs2[0];
    __syncthreads();
    if (a<APN){
      size_t u = u0+q;
      out[u*APN + a]                     = acc[q];   // UA_ori
      out[(size_t)UEN*APN   + u*APN + a] = e1/s1;    // UA_de
      out[(size_t)2*UEN*APN + u*APN + a] = e2/s2;    // UA_st
    }
  }
}

extern "C" void kernel_launch(void* const* d_in, const int* in_sizes, int n_in,
                              void* d_out, int out_size, void* d_ws, size_t ws_size,
                              hipStream_t stream) {
  const float* pl      = (const float*)d_in[0];
  const int*   adj_ue  = (const int*)d_in[2];
  const int*   adj_ap  = (const int*)d_in[3];
  const float* W1ap1   = (const float*)d_in[4];
  const float* W1ap2   = (const float*)d_in[5];
  const float* W1ue1   = (const float*)d_in[6];
  const float* W1ue2   = (const float*)d_in[7];
  const float* W2ap1   = (const float*)d_in[8];
  const float* W2ap2   = (const float*)d_in[9];
  const float* W2ue1   = (const float*)d_in[10];
  const float* W2ue2   = (const float*)d_in[11];
  const float* wap1    = (const float*)d_in[12];
  const float* wap2    = (const float*)d_in[13];
  const float* bais_ap = (const float*)d_in[14];
  const float* wue     = (const float*)d_in[15];
  const float* bais_ue = (const float*)d_in[16];
  const float* gamma   = (const float*)d_in[17];
  const float* beta    = (const float*)d_in[18];
  float* out = (float*)d_out;
  (void)in_sizes; (void)n_in; (void)out_size; (void)ws_size;

  char* ws = (char*)d_ws;
  size_t off = 0;
  auto alloc = [&](size_t bytes)->char*{
    char* p = ws + off; off += (bytes + 255) & ~(size_t)255; return p;
  };
  int*   ap2ap = (int*)alloc(APN*SS*4);
  int*   ue2ue = (int*)alloc(UEN*SS*4);
  float* Xap   = (float*)alloc((size_t)APN*H2*4);
  float* Xue   = (float*)alloc((size_t)UEN*H2*4);   // phase1: gemA partials
  float* X2ue  = (float*)alloc((size_t)UEN*H2*4);   // phase1: T3|T4
  float* part  = (float*)alloc(32*512*4);
  float* scsh  = (float*)alloc(2*H2*4);
  // ws-buffer aliases (dead-before-write ordering):
  float* partialA = Xue;               // 16*105*128 = 215,040 fl, dead after k_redA
  float* T3 = X2ue;                    // 512,000 fl, dead after k_x_ueB
  float* T4 = X2ue + 512000;           // 512,000 fl, dead after k_x_ueB
  // d_out scratch map (floats; out_size = 1,260,106; all dead before final writes):
  float* U1  = out;                    // 512,000; dead after k_x_ap
  float* Yb8 = out;                    // aliases U1 (k_gemC runs after k_x_ap)
  float* R4  = out + 520000;           // 512,000; dead after k_x_ueB
  float* RA  = out + 1040000;          // 4*105*128 = 53,760 (G1,G2a,Q2,P3)
  float* P3t = RA + (size_t)3*APN*H;
  float* P7t = out + 1100000;          // 13,440

  k_twohop        <<<dim3(((APN+UEN)*SS+255)/256), 256, 0, stream>>>(adj_ue, adj_ap, ap2ap, ue2ue);
  k_gemA4         <<<dim3(APN,4,4), 128, 0, stream>>>(pl, W1ap1, W1ap2, W1ue1, partialA);
  k_redA          <<<dim3((4*APN*H+255)/256), 256, 0, stream>>>(partialA, RA);
  k_gemB          <<<dim3((UEN+63)/64, 4), 256, 0, stream>>>(pl, W1ap1, W1ue1, W1ue2,
                                                             T3, T4, U1, R4);
  k_x_ueB         <<<dim3(UEN), 256, 0, stream>>>(T3, T4, P3t, R4, adj_ue, ue2ue, Xue);
  k_x_ap          <<<dim3(APN), 256, 0, stream>>>(RA, U1, adj_ap, ap2ap, Xap);
  k_p7            <<<dim3(APN), 128, 0, stream>>>(Xap, W2ue1, P7t);
  k_gemC          <<<dim3((UEN+63)/64, 3), 256, 0, stream>>>(Xue, W2ue1, W2ue2, X2ue, Yb8);
  k_ap_layer2_head<<<dim3(APN), 256, 0, stream>>>(Xap, Xue, W2ap1, W2ap2, adj_ap, ap2ap,
                                                  wap1, wap2, bais_ap,
                                                  out + (size_t)3*UEN*APN);
  k_x7x8b         <<<dim3(UEN), 256, 0, stream>>>(X2ue, P7t, Yb8, adj_ue, ue2ue);
  k_bn_part       <<<dim3(32), 256, 0, stream>>>(X2ue, part);
  k_bn_final      <<<dim3(1), 256, 0, stream>>>(part, gamma, beta, wue, scsh,
                                                out + (size_t)3*UEN*APN + APN);
  k_ua_head       <<<dim3(UEN/4), 128, 0, stream>>>(X2ue, scsh, wue, bais_ue, out);
}